// Round 12
// baseline (175.141 us; speedup 1.0000x reference)
//
#include <hip/hip_runtime.h>
#include <hip/hip_bf16.h>

// ---- types ----
typedef short bf16x8 __attribute__((ext_vector_type(8)));          // 8 bf16 = 4 VGPRs (MFMA A/B frag)
typedef unsigned short u16x8 __attribute__((ext_vector_type(8)));
typedef unsigned short u16x4 __attribute__((ext_vector_type(4)));
typedef float f32x4 __attribute__((ext_vector_type(4)));           // MFMA C/D frag

typedef unsigned int __attribute__((address_space(1))) gu32;       // global
typedef unsigned int __attribute__((address_space(3))) lu32;       // LDS

#define MFMA16(a, b, c) __builtin_amdgcn_mfma_f32_16x16x32_bf16((a), (b), (c), 0, 0, 0)

constexpr int SEQ = 2048;
constexpr int NH = 16;
constexpr int NTOK = 2 * SEQ;  // 4096

__device__ __forceinline__ float bf2f(unsigned short u) {
  union { unsigned int i; float f; } v; v.i = ((unsigned int)u) << 16; return v.f;
}
__device__ __forceinline__ unsigned short f2bf(float f) {
  __hip_bfloat16 h = __float2bfloat16(f);   // RNE
  return __builtin_bit_cast(unsigned short, h);
}
// pack two fp32 -> bf16 pair by TRUNCATION via one v_perm_b32 (hi<<16 | lo)
__device__ __forceinline__ unsigned int pkbf_trunc(float hi, float lo) {
  return __builtin_amdgcn_perm(__builtin_bit_cast(unsigned int, hi),
                               __builtin_bit_cast(unsigned int, lo), 0x07060302u);
}
__device__ __forceinline__ u16x8 cvt8(const float* __restrict__ p) {
  f32x4 a = *(const f32x4*)p;
  f32x4 b = *(const f32x4*)(p + 4);
  u16x8 r;
#pragma unroll
  for (int j = 0; j < 4; j++) { r[j] = f2bf(a[j]); r[4 + j] = f2bf(b[j]); }
  return r;
}

// =====================================================================
// Convert pass v2: flat balanced 1-D grid (r10).
// =====================================================================
__global__ __launch_bounds__(256) void cvt_all(
    const float* __restrict__ x, const float* __restrict__ wq, const float* __restrict__ wk,
    const float* __restrict__ wv, const float* __restrict__ wo,
    unsigned short* __restrict__ Xb, unsigned short* __restrict__ Wb) {
  const size_t XN = (size_t)NTOK * 1024;        // 4M
  const size_t TOT = XN + (size_t)4 * 1024 * 1024;  // 8M
  for (size_t i = ((size_t)blockIdx.x * 256 + threadIdx.x) * 8; i < TOT;
       i += (size_t)gridDim.x * 256 * 8) {
    if (i < XN) {
      *(u16x8*)(Xb + i) = cvt8(x + i);
    } else {
      const size_t j = i - XN;
      const int w = (int)(j >> 20);   // which 1M-elem weight
      const float* src = (w == 0) ? wq : (w == 1) ? wk : (w == 2) ? wv : wo;
      *(u16x8*)(Wb + j) = cvt8(src + (j & (((size_t)1 << 20) - 1)));
    }
  }
}

// =====================================================================
// Async global->LDS staging with XOR-chunk permutation (verified r3):
// 16B chunk (row, c8) -> slot row*8 + (c8 ^ (row&7)).
// =====================================================================
template <int ROWS, int NWAVE>
__device__ __forceinline__ void stage_glds(const unsigned short* __restrict__ gbase,
                                           int rstride,
                                           unsigned short* __restrict__ lds,
                                           int wid, int lane) {
  constexpr int ISS = ROWS * 8 / (NWAVE * 64);
#pragma unroll
  for (int t = 0; t < ISS; ++t) {
    const int slot = (wid * ISS + t) * 64 + lane;
    const int row = slot >> 3;
    const int c8 = (slot & 7) ^ (row & 7);
    const unsigned short* gp = gbase + (size_t)row * rstride + c8 * 8;
    unsigned short* lp = lds + (size_t)(wid * ISS + t) * 512;   // wave-uniform, 1 KiB/issue
    __builtin_amdgcn_global_load_lds((const gu32*)gp, (lu32*)lp, 16, 0, 0);
  }
}

__device__ __forceinline__ bf16x8 frag_ld(const unsigned short* __restrict__ lds, int row, int c8) {
  const int slot = row * 8 + (c8 ^ (row & 7));
  return *(const bf16x8*)(lds + slot * 8);
}

#define SBAR do { __builtin_amdgcn_sched_barrier(0); \
                  asm volatile("s_barrier" ::: "memory"); \
                  __builtin_amdgcn_sched_barrier(0); } while (0)

// =====================================================================
// Output projection r12: attn-v14-style single-barrier double-buffered
// GEMM. 128x64 tile, 4 waves, same frag mapping/epilogue as the proven
// gemm_lds, but ONE plain __syncthreads per K-tile (16 vs 32 barriers,
// no head-of-compute vmcnt(0) drain). Per iter: barrier (drains glds
// of tile t staged last iter; frees buf^1) -> issue stage(t+1)->buf^1
// -> compute tile t from buf (hides stage latency under full compute
// phase). No inline-asm fences: compiler stays free (r9 lesson — SBAR
// pinning at 2 blocks/CU regressed). Race audit == attn v14's.
// =====================================================================
__global__ __launch_bounds__(256) void gemm_op_v14(
    const unsigned short* __restrict__ A,   // [4096][1024] bf16 (attn out)
    const unsigned short* __restrict__ B,   // [1024][1024] bf16 (Wo rows)
    float* __restrict__ C) {                // [4096][1024] fp32
  constexpr int K = 1024;
  constexpr int MI = 4, NI = 2;
  __shared__ __align__(16) unsigned short As[2][128 * 64];   // 16 KiB x2
  __shared__ __align__(16) unsigned short Bs[2][64 * 64];    // 8 KiB x2

  const int tid = threadIdx.x;
  const int wid = tid >> 6, lane = tid & 63;
  const int quad = lane >> 4, c16 = lane & 15;
  const int wrow = wid >> 1, wcol = wid & 1;

  const int m0 = blockIdx.x * 128;   // m fastest -> same-A blocks share an XCD
  const int n0 = blockIdx.y * 64;

  const unsigned short* Abase = A + (size_t)m0 * K;
  const unsigned short* Bbase = B + (size_t)n0 * K;

  f32x4 acc[MI][NI];
#pragma unroll
  for (int i = 0; i < MI; i++)
#pragma unroll
    for (int j = 0; j < NI; j++) acc[i][j] = f32x4{0.f, 0.f, 0.f, 0.f};

  // prologue: stage tile 0 -> buf 0
  stage_glds<128, 4>(Abase, K, As[0], wid, lane);
  stage_glds<64, 4>(Bbase, K, Bs[0], wid, lane);

  for (int t = 0; t < 16; ++t) {
    const int buf = t & 1;
    // ONE barrier: drains this wave's glds (tile t landed), publishes,
    // and frees buf^1 (its readers all retired before this barrier).
    __syncthreads();
    if (t + 1 < 16) {   // stage next tile into the other buffer
      stage_glds<128, 4>(Abase + (t + 1) * 64, K, As[buf ^ 1], wid, lane);
      stage_glds<64, 4>(Bbase + (t + 1) * 64, K, Bs[buf ^ 1], wid, lane);
    }
#pragma unroll
    for (int ks = 0; ks < 2; ++ks) {
      bf16x8 af[MI], bfr[NI];
#pragma unroll
      for (int i = 0; i < MI; i++)
        af[i] = frag_ld(As[buf], wrow * 64 + i * 16 + c16, ks * 4 + quad);
#pragma unroll
      for (int j = 0; j < NI; j++)
        bfr[j] = frag_ld(Bs[buf], wcol * 32 + j * 16 + c16, ks * 4 + quad);
#pragma unroll
      for (int i = 0; i < MI; i++)
#pragma unroll
        for (int j = 0; j < NI; j++) acc[i][j] = MFMA16(af[i], bfr[j], acc[i][j]);
    }
  }

#pragma unroll
  for (int i = 0; i < MI; i++) {
#pragma unroll
    for (int j = 0; j < NI; j++) {
      const int row = m0 + wrow * 64 + i * 16 + quad * 4;
      const int col = n0 + wcol * 32 + j * 16 + c16;
#pragma unroll
      for (int r = 0; r < 4; r++)
        C[(size_t)(row + r) * 1024 + col] = acc[i][j][r];
    }
  }
}

// =====================================================================
// QKV projection: 256x192-tile GEMM, FOUR merged phases/iteration
// (verified r11: total -3.7 µs). vmcnt(3) at P34/P78.
// =====================================================================
__global__ __launch_bounds__(512) void gemm_4ph_w192(
    const unsigned short* __restrict__ A,   // [4096][1024] bf16
    const unsigned short* __restrict__ B,   // [3072][1024] bf16 (Wq|Wk|Wv rows)
    unsigned short* __restrict__ C) {       // [4096][3072] bf16
  constexpr int K = 1024;
  __shared__ __align__(16) unsigned short As[2][256 * 64];   // 32 KiB x2
  __shared__ __align__(16) unsigned short Bs[2][192 * 64];   // 24 KiB x2

  const int tid = threadIdx.x;
  const int wid = tid >> 6, lane = tid & 63;
  const int quad = lane >> 4, c16 = lane & 15;
  const int wr = wid >> 2;        // 0..1  -> 128 output rows
  const int wc = wid & 3;         // 0..3  -> 48 output cols

  const int bid = blockIdx.x;
  const int swz = (bid & 7) * 32 + (bid >> 3);
  const int m0 = (swz >> 4) * 256;
  const int n0 = (swz & 15) * 192;

  const unsigned short* Abase = A + (size_t)m0 * K;
  const unsigned short* Bbase = B + (size_t)n0 * K;

  f32x4 acc[8][3];
#pragma unroll
  for (int i = 0; i < 8; i++)
#pragma unroll
    for (int j = 0; j < 3; j++) acc[i][j] = f32x4{0.f, 0.f, 0.f, 0.f};

  bf16x8 af[4][2];   // 4 m-rows x 2 ks (both K-slices live per phase)
  bf16x8 bf0[3];     // B frags ks=0
  bf16x8 bf1[3];     // B frags ks=1

  auto lda8 = [&](const unsigned short* asb, int mo) {
#pragma unroll
    for (int mi = 0; mi < 4; mi++)
#pragma unroll
      for (int ks = 0; ks < 2; ks++)
        af[mi][ks] = frag_ld(asb, wr * 128 + (mo + mi) * 16 + c16, ks * 4 + quad);
  };
  auto ldb6 = [&](const unsigned short* bsb) {
#pragma unroll
    for (int ni = 0; ni < 3; ni++) {
      bf0[ni] = frag_ld(bsb, wc * 48 + ni * 16 + c16, quad);
      bf1[ni] = frag_ld(bsb, wc * 48 + ni * 16 + c16, 4 + quad);
    }
  };
  auto mm24 = [&](int mo) {   // 24-MFMA merged phase
    __builtin_amdgcn_s_setprio(1);
#pragma unroll
    for (int mi = 0; mi < 4; mi++)
#pragma unroll
      for (int ni = 0; ni < 3; ni++) {
        acc[mo + mi][ni] = MFMA16(af[mi][0], bf0[ni], acc[mo + mi][ni]);
        acc[mo + mi][ni] = MFMA16(af[mi][1], bf1[ni], acc[mo + mi][ni]);
      }
    __builtin_amdgcn_s_setprio(0);
  };

  // ---- prologue: B(0):3, A(0):4, B(1):3 -> vmcnt(3) leaves B(1)
  stage_glds<192, 8>(Bbase, K, Bs[0], wid, lane);
  stage_glds<128, 8>(Abase, K, As[0], wid, lane);
  stage_glds<128, 8>(Abase + (size_t)128 * K, K, As[0] + 8192, wid, lane);
  stage_glds<192, 8>(Bbase + 64, K, Bs[1], wid, lane);
  asm volatile("s_waitcnt vmcnt(3)" ::: "memory");   // tile 0 landed
  SBAR;

  for (int i = 0; i < 7; ++i) {
    const int t = 2 * i;
    const int kb1 = (t + 1) * 64, kb2 = (t + 2) * 64, kb3 = (t + 3) * 64;
    // P12: tile t mo0 (both ks); stage A(t+1) h0+h1 -> As1
    lda8(As[0], 0); ldb6(Bs[0]);
    stage_glds<128, 8>(Abase + kb1, K, As[1], wid, lane);
    stage_glds<128, 8>(Abase + (size_t)128 * K + kb1, K, As[1] + 8192, wid, lane);
    mm24(0); SBAR;
    // P34: tile t mo4; stage B(t+2)->Bs0; vmcnt(3) -> t+1 landed
    lda8(As[0], 4);
    stage_glds<192, 8>(Bbase + kb2, K, Bs[0], wid, lane);
    asm volatile("s_waitcnt vmcnt(3)" ::: "memory");
    mm24(4); SBAR;
    // P56: tile t+1 mo0; stage A(t+2)->As0
    lda8(As[1], 0); ldb6(Bs[1]);
    stage_glds<128, 8>(Abase + kb2, K, As[0], wid, lane);
    stage_glds<128, 8>(Abase + (size_t)128 * K + kb2, K, As[0] + 8192, wid, lane);
    mm24(0); SBAR;
    // P78: tile t+1 mo4; stage B(t+3)->Bs1; vmcnt(3) -> t+2 landed
    lda8(As[1], 4);
    stage_glds<192, 8>(Bbase + kb3, K, Bs[1], wid, lane);
    asm volatile("s_waitcnt vmcnt(3)" ::: "memory");
    mm24(4); SBAR;
  }

  // ---- final pair: t=14 (buf0), t=15 (buf1); stage only A(15)
  {
    const int kb1 = 15 * 64;
    lda8(As[0], 0); ldb6(Bs[0]);
    stage_glds<128, 8>(Abase + kb1, K, As[1], wid, lane);
    stage_glds<128, 8>(Abase + (size_t)128 * K + kb1, K, As[1] + 8192, wid, lane);
    mm24(0); SBAR;
    lda8(As[0], 4);
    asm volatile("s_waitcnt vmcnt(0)" ::: "memory");   // drains A(15)+B(15)
    mm24(4); SBAR;
    lda8(As[1], 0); ldb6(Bs[1]);
    mm24(0); SBAR;
    lda8(As[1], 4);
    mm24(4);
  }

#pragma unroll
  for (int mi = 0; mi < 8; mi++) {
#pragma unroll
    for (int ni = 0; ni < 3; ni++) {
      const int row = m0 + wr * 128 + mi * 16 + quad * 4;
      const int col = n0 + wc * 48 + ni * 16 + c16;
#pragma unroll
      for (int r = 0; r < 4; r++)
        C[(size_t)(row + r) * 3072 + col] = f2bf(acc[mi][ni][r]);
    }
  }
}

// =====================================================================
// Flash attention v14 (causal) — single-barrier pipeline, Vt dbuf
// (verified r7-r11: 41.3-42.8 µs). Structural floor. FROZEN.
// =====================================================================
__device__ __forceinline__ int vt_idx(int d, int kv) {
  int ck = kv >> 3;
  int s = ((d >> 3) ^ d) & 7;
  return d * 64 + ((ck ^ s) << 3) + (kv & 7);
}

struct AttnShared {
  unsigned short Kt[2][64 * 64];   // XOR-chunk swizzled K rows (8 KB x2)
  unsigned short Vt[2][64 * 64];   // vt_idx-swizzled V^T (8 KB x2)
  unsigned short Pt[4][16 * 64];   // per-wave 16x64 XOR-chunk P^T tile (8 KB)
};

__global__ __launch_bounds__(256) void attn_kernel(
    const unsigned short* __restrict__ QKV,   // [NTOK][3072]: Q | K | V (bf16)
    unsigned short* __restrict__ Oa) {        // [NTOK][1024] bf16
  __shared__ AttnShared sh;
  const int h = blockIdx.x;
  const int b = blockIdx.y;
  const int t = 31 - blockIdx.z;   // long tiles first (z is slowest dim)
  const int tid = threadIdx.x;
  const int wid = tid >> 6, lane = tid & 63;
  const int quad = lane >> 4, c16 = lane & 15;
  const size_t tokbase = (size_t)b * SEQ;
  const int q0 = t * 64;
  const int nkv = t + 1;

  // Q fragments (B-operand), scaled by 0.125 * log2(e)
  const unsigned short* qp = QKV + (tokbase + q0 + wid * 16 + c16) * 3072 + h * 64;
  bf16x8 qf[2];
#pragma unroll
  for (int ks = 0; ks < 2; ++ks) {
    u16x8 u = *(const u16x8*)(qp + ks * 32 + quad * 8);
    bf16x8 tq;
#pragma unroll
    for (int j = 0; j < 8; j++) tq[j] = (short)f2bf(0.1803368801f * bf2f(u[j]));
    qf[ks] = tq;
  }

  const unsigned short* kbase = QKV + tokbase * 3072 + 1024 + h * 64;
  const unsigned short* vbase = QKV + tokbase * 3072 + 2048 + h * 64;
  const int vkv = (tid >> 4) * 4;   // V stager: 4 kv rows
  const int vd = (tid & 15) * 4;    //           4 d cols

  f32x4 o[4];
  float lacc = 0.f;
#pragma unroll
  for (int nt = 0; nt < 4; nt++) o[nt] = f32x4{0.f, 0.f, 0.f, 0.f};
  unsigned short* PtW = sh.Pt[wid];
  const int pt_sub = (quad & 1) * 4;
  const int pt_c8h = quad >> 1;

  // ---- prologue: stage Kt[0]; load V(0) regs; write Vt[0] (pre-barrier)
  stage_glds<64, 4>(kbase, 3072, sh.Kt[0], wid, lane);
  u16x4 vr[4];
#pragma unroll
  for (int i = 0; i < 4; i++)
    vr[i] = *(const u16x4*)(vbase + (size_t)(vkv + i) * 3072 + vd);
#pragma unroll
  for (int dd = 0; dd < 4; ++dd) {   // compiler inserts vmcnt wait on vr here
    uint2 w;
    w.x = (unsigned int)vr[0][dd] | ((unsigned int)vr[1][dd] << 16);
    w.y = (unsigned int)vr[2][dd] | ((unsigned int)vr[3][dd] << 16);
    *(uint2*)&sh.Vt[0][vt_idx(vd + dd, vkv)] = w;
  }

  for (int kt = 0; kt < nkv; ++kt) {
    const int buf = kt & 1;
    // ONE barrier: publishes Vt[buf] writes (prev iter / prologue), drains
    // Kt[buf] glds (syncthreads waits vmcnt 0), frees Vt[buf^1]+Kt[buf^1].
    __syncthreads();

    const bool pf = (kt + 1 < nkv);
    if (pf) {   // issue next tile's K glds + V reg loads (fly over compute)
      const size_t nofs = (size_t)(kt + 1) * 64;
      stage_glds<64, 4>(kbase + nofs * 3072, 3072, sh.Kt[buf ^ 1], wid, lane);
#pragma unroll
      for (int i = 0; i < 4; i++)
        vr[i] = *(const u16x4*)(vbase + (nofs + vkv + i) * 3072 + vd);
    }

    // ---- S^T = K (Q*scale*log2e)^T - 16 : lane holds (kv=nt*16+quad*4+r, q=c16) ----
    const unsigned short* KtB = sh.Kt[buf];
    f32x4 st[4];
    __builtin_amdgcn_s_setprio(1);   // T5
#pragma unroll
    for (int nt = 0; nt < 4; ++nt) {
      f32x4 a = f32x4{-16.f, -16.f, -16.f, -16.f};
      a = MFMA16(frag_ld(KtB, nt * 16 + c16, quad), qf[0], a);
      a = MFMA16(frag_ld(KtB, nt * 16 + c16, 4 + quad), qf[1], a);
      st[nt] = a;
    }
    __builtin_amdgcn_s_setprio(0);
    if (kt == nkv - 1) {   // diagonal kv-tile
      const int kv0 = kt * 64;
      const int qg = q0 + wid * 16 + c16;
#pragma unroll
      for (int nt = 0; nt < 4; nt++)
#pragma unroll
        for (int r = 0; r < 4; r++) {
          int kg = kv0 + nt * 16 + quad * 4 + r;
          if (kg > qg) st[nt][r] = -1e30f;
        }
    }

    // ---- p = exp2(s); v_perm trunc-pack; XOR-chunk Pt writes ----
#pragma unroll
    for (int nt = 0; nt < 4; nt++) {
      float p0 = __builtin_amdgcn_exp2f(st[nt][0]);
      float p1 = __builtin_amdgcn_exp2f(st[nt][1]);
      float p2 = __builtin_amdgcn_exp2f(st[nt][2]);
      float p3 = __builtin_amdgcn_exp2f(st[nt][3]);
      lacc += (p0 + p1) + (p2 + p3);
      uint2 w;
      w.x = pkbf_trunc(p1, p0);
      w.y = pkbf_trunc(p3, p2);
      const int c8w = 2 * nt + pt_c8h;
      const int slot = c16 * 8 + (c8w ^ (c16 & 7));
      *(uint2*)&PtW[slot * 8 + pt_sub] = w;
    }

    if (pf) {   // write NEXT tile's V into the other Vt buffer (no barrier
                // needed before PV: PV reads Vt[buf], writes go to Vt[buf^1])
#pragma unroll
      for (int dd = 0; dd < 4; ++dd) {   // compiler vmcnt-waits on vr
        uint2 w;
        w.x = (unsigned int)vr[0][dd] | ((unsigned int)vr[1][dd] << 16);
        w.y = (unsigned int)vr[2][dd] | ((unsigned int)vr[3][dd] << 16);
        *(uint2*)&sh.Vt[buf ^ 1][vt_idx(vd + dd, vkv)] = w;
      }
    }

    // ---- O^T += V^T P^T (wave-private Pt; lgkmcnt-ordered, no barrier) ----
    const unsigned short* VtB = sh.Vt[buf];
    __builtin_amdgcn_s_setprio(1);   // T5
#pragma unroll
    for (int ks = 0; ks < 2; ++ks) {
      bf16x8 pfrag = frag_ld(PtW, c16, ks * 4 + quad);
#pragma unroll
      for (int nt2 = 0; nt2 < 4; ++nt2) {
        bf16x8 vf = *(const bf16x8*)&VtB[vt_idx(nt2 * 16 + c16, ks * 32 + quad * 8)];
        o[nt2] = MFMA16(vf, pfrag, o[nt2]);
      }
    }
    __builtin_amdgcn_s_setprio(0);
  }

  // ---- epilogue: l across quads (2 shuffles); packed dwordx2 stores ----
  lacc += __shfl_xor(lacc, 16);
  lacc += __shfl_xor(lacc, 32);
  const float linv = 1.f / lacc;
  const size_t row = tokbase + q0 + wid * 16 + c16;
#pragma unroll
  for (int nt2 = 0; nt2 < 4; nt2++) {
    uint2 w;
    w.x = (unsigned int)f2bf(o[nt2][0] * linv) | ((unsigned int)f2bf(o[nt2][1] * linv) << 16);
    w.y = (unsigned int)f2bf(o[nt2][2] * linv) | ((unsigned int)f2bf(o[nt2][3] * linv) << 16);
    *(uint2*)&Oa[row * 1024 + h * 64 + nt2 * 16 + quad * 4] = w;
  }
}

// =====================================================================
// Round-2 fallback GEMM (fp32 staging) — used only if ws_size < 40 MB.
// =====================================================================
template <int BM, int BN, int LDC, bool AF32, bool CF32>
__global__ __launch_bounds__(256) void gemm_bt(
    const void* __restrict__ Av, const float* __restrict__ W0, const float* __restrict__ W1,
    const float* __restrict__ W2, void* __restrict__ Cv) {
  constexpr int K = 1024;
  constexpr int LDS_LD = 72;
  constexpr int MI = BM / 32, NI = BN / 32;
  __shared__ __align__(16) unsigned short As[BM][LDS_LD];
  __shared__ __align__(16) unsigned short Bs[BN][LDS_LD];
  const int tid = threadIdx.x, wid = tid >> 6, lane = tid & 63;
  const int quad = lane >> 4, c16 = lane & 15;
  const int wrow = wid >> 1, wcol = wid & 1;
  const float* W = (blockIdx.z == 0) ? W0 : (blockIdx.z == 1 ? W1 : W2);
  const int m0 = blockIdx.y * BM, n0 = blockIdx.x * BN, cofs = blockIdx.z * 1024;
  f32x4 acc[MI][NI];
#pragma unroll
  for (int i = 0; i < MI; i++)
#pragma unroll
    for (int j = 0; j < NI; j++) acc[i][j] = f32x4{0.f, 0.f, 0.f, 0.f};
  for (int kb = 0; kb < K; kb += 64) {
    __syncthreads();
#pragma unroll
    for (int c = tid; c < BM * 8; c += 256) {
      int row = c >> 3, c8 = c & 7;
      if constexpr (AF32)
        *(u16x8*)&As[row][c8 * 8] = cvt8((const float*)Av + (size_t)(m0 + row) * K + kb + c8 * 8);
      else
        *(u16x8*)&As[row][c8 * 8] = *(const u16x8*)((const unsigned short*)Av + (size_t)(m0 + row) * K + kb + c8 * 8);
    }
#pragma unroll
    for (int c = tid; c < BN * 8; c += 256) {
      int row = c >> 3, c8 = c & 7;
      *(u16x8*)&Bs[row][c8 * 8] = cvt8(W + (size_t)(n0 + row) * K + kb + c8 * 8);
    }
    __syncthreads();
#pragma unroll
    for (int ks = 0; ks < 2; ++ks) {
      bf16x8 af[MI], bfr[NI];
#pragma unroll
      for (int i = 0; i < MI; i++)
        af[i] = *(const bf16x8*)&As[wrow * (BM / 2) + i * 16 + c16][ks * 32 + quad * 8];
#pragma unroll
      for (int j = 0; j < NI; j++)
        bfr[j] = *(const bf16x8*)&Bs[wcol * (BN / 2) + j * 16 + c16][ks * 32 + quad * 8];
#pragma unroll
      for (int i = 0; i < MI; i++)
#pragma unroll
        for (int j = 0; j < NI; j++) acc[i][j] = MFMA16(af[i], bfr[j], acc[i][j]);
    }
  }
#pragma unroll
  for (int i = 0; i < MI; i++)
#pragma unroll
    for (int j = 0; j < NI; j++) {
      int row = m0 + wrow * (BM / 2) + i * 16 + quad * 4;
      int col = n0 + wcol * (BN / 2) + j * 16 + c16 + cofs;
#pragma unroll
      for (int r = 0; r < 4; r++) {
        if constexpr (CF32) ((float*)Cv)[(size_t)(row + r) * LDC + col] = acc[i][j][r];
        else ((unsigned short*)Cv)[(size_t)(row + r) * LDC + col] = f2bf(acc[i][j][r]);
      }
    }
}

// =====================================================================
extern "C" void kernel_launch(void* const* d_in, const int* in_sizes, int n_in,
                              void* d_out, int out_size, void* d_ws, size_t ws_size,
                              hipStream_t stream) {
  const float* x = (const float*)d_in[0];
  const float* Wq = (const float*)d_in[2];
  const float* Wk = (const float*)d_in[3];
  const float* Wv = (const float*)d_in[4];
  const float* Wo = (const float*)d_in[5];
  float* out = (float*)d_out;

  unsigned short* QKV = (unsigned short*)d_ws;                 // [4096][3072] bf16 (24MB)
  unsigned short* Wb = QKV + (size_t)NTOK * 3072;              // 4 x [1024][1024] bf16 (8MB)
  unsigned short* Xb = Wb + (size_t)4 * 1024 * 1024;           // [4096][1024] bf16 (8MB), == AT
  unsigned short* AT = Xb;

  if (ws_size >= (size_t)40 * 1024 * 1024) {
    // convert: flat balanced grid (2048 blocks, 2 iters/thread exactly)
    cvt_all<<<dim3(2048), 256, 0, stream>>>(x, Wq, Wk, Wv, Wo, Xb, Wb);
    // fused QKV projection: 256x192, FOUR merged phases (r11)
    gemm_4ph_w192<<<dim3(256), 512, 0, stream>>>(Xb, Wb, QKV);
    // flash attention v14: single-barrier pipeline, Vt double-buffer
    attn_kernel<<<dim3(NH, 2, 32), 256, 0, stream>>>(QKV, AT);
    // output projection: attn-v14-style single-barrier dbuf (r12)
    gemm_op_v14<<<dim3(32, 16), 256, 0, stream>>>(
        AT, Wb + (size_t)3 * 1024 * 1024, out);
  } else {
    unsigned short* QKV2 = (unsigned short*)d_ws;
    unsigned short* AT2 = QKV2 + (size_t)NTOK * 3072;
    gemm_bt<128, 128, 3072, true, false><<<dim3(8, 32, 3), 256, 0, stream>>>(x, Wq, Wk, Wv, QKV2);
    attn_kernel<<<dim3(NH, 2, 32), 256, 0, stream>>>(QKV2, AT2);
    gemm_bt<64, 64, 1024, false, true><<<dim3(16, 64, 1), 256, 0, stream>>>(AT2, Wo, Wo, Wo, out);
  }
}

// Round 13
// 171.562 us; speedup vs baseline: 1.0209x; 1.0209x over previous
//
#include <hip/hip_runtime.h>
#include <hip/hip_bf16.h>

// ---- types ----
typedef short bf16x8 __attribute__((ext_vector_type(8)));          // 8 bf16 = 4 VGPRs (MFMA A/B frag)
typedef unsigned short u16x8 __attribute__((ext_vector_type(8)));
typedef unsigned short u16x4 __attribute__((ext_vector_type(4)));
typedef float f32x4 __attribute__((ext_vector_type(4)));           // MFMA C/D frag

typedef unsigned int __attribute__((address_space(1))) gu32;       // global
typedef unsigned int __attribute__((address_space(3))) lu32;       // LDS

#define MFMA16(a, b, c) __builtin_amdgcn_mfma_f32_16x16x32_bf16((a), (b), (c), 0, 0, 0)

constexpr int SEQ = 2048;
constexpr int NH = 16;
constexpr int NTOK = 2 * SEQ;  // 4096

__device__ __forceinline__ float bf2f(unsigned short u) {
  union { unsigned int i; float f; } v; v.i = ((unsigned int)u) << 16; return v.f;
}
__device__ __forceinline__ unsigned short f2bf(float f) {
  __hip_bfloat16 h = __float2bfloat16(f);   // RNE
  return __builtin_bit_cast(unsigned short, h);
}
// pack two fp32 -> bf16 pair by TRUNCATION via one v_perm_b32 (hi<<16 | lo)
__device__ __forceinline__ unsigned int pkbf_trunc(float hi, float lo) {
  return __builtin_amdgcn_perm(__builtin_bit_cast(unsigned int, hi),
                               __builtin_bit_cast(unsigned int, lo), 0x07060302u);
}
__device__ __forceinline__ u16x8 cvt8(const float* __restrict__ p) {
  f32x4 a = *(const f32x4*)p;
  f32x4 b = *(const f32x4*)(p + 4);
  u16x8 r;
#pragma unroll
  for (int j = 0; j < 4; j++) { r[j] = f2bf(a[j]); r[4 + j] = f2bf(b[j]); }
  return r;
}

// =====================================================================
// Convert pass v2: flat balanced 1-D grid (r10).
// =====================================================================
__global__ __launch_bounds__(256) void cvt_all(
    const float* __restrict__ x, const float* __restrict__ wq, const float* __restrict__ wk,
    const float* __restrict__ wv, const float* __restrict__ wo,
    unsigned short* __restrict__ Xb, unsigned short* __restrict__ Wb) {
  const size_t XN = (size_t)NTOK * 1024;        // 4M
  const size_t TOT = XN + (size_t)4 * 1024 * 1024;  // 8M
  for (size_t i = ((size_t)blockIdx.x * 256 + threadIdx.x) * 8; i < TOT;
       i += (size_t)gridDim.x * 256 * 8) {
    if (i < XN) {
      *(u16x8*)(Xb + i) = cvt8(x + i);
    } else {
      const size_t j = i - XN;
      const int w = (int)(j >> 20);   // which 1M-elem weight
      const float* src = (w == 0) ? wq : (w == 1) ? wk : (w == 2) ? wv : wo;
      *(u16x8*)(Wb + j) = cvt8(src + (j & (((size_t)1 << 20) - 1)));
    }
  }
}

// =====================================================================
// Async global->LDS staging with XOR-chunk permutation (verified r3):
// 16B chunk (row, c8) -> slot row*8 + (c8 ^ (row&7)).
// =====================================================================
template <int ROWS, int NWAVE>
__device__ __forceinline__ void stage_glds(const unsigned short* __restrict__ gbase,
                                           int rstride,
                                           unsigned short* __restrict__ lds,
                                           int wid, int lane) {
  constexpr int ISS = ROWS * 8 / (NWAVE * 64);
#pragma unroll
  for (int t = 0; t < ISS; ++t) {
    const int slot = (wid * ISS + t) * 64 + lane;
    const int row = slot >> 3;
    const int c8 = (slot & 7) ^ (row & 7);
    const unsigned short* gp = gbase + (size_t)row * rstride + c8 * 8;
    unsigned short* lp = lds + (size_t)(wid * ISS + t) * 512;   // wave-uniform, 1 KiB/issue
    __builtin_amdgcn_global_load_lds((const gu32*)gp, (lu32*)lp, 16, 0, 0);
  }
}

__device__ __forceinline__ bf16x8 frag_ld(const unsigned short* __restrict__ lds, int row, int c8) {
  const int slot = row * 8 + (c8 ^ (row & 7));
  return *(const bf16x8*)(lds + slot * 8);
}

#define SBAR do { __builtin_amdgcn_sched_barrier(0); \
                  asm volatile("s_barrier" ::: "memory"); \
                  __builtin_amdgcn_sched_barrier(0); } while (0)

// =====================================================================
// m97-style bf16 GEMM, XCD-local grid — PROVEN for the OUTPUT
// projection. r9 (counted-vmcnt rewrite, +1.3) and r12 (single-barrier
// v14-style, +4.9) both regressed vs this: at 2 blocks/CU the
// co-resident block hides the stage latency; burst-stage-between-
// barriers is locally optimal. FROZEN — do not touch again.
// =====================================================================
template <int BM, int BN, int LDC, bool CF32>
__global__ __launch_bounds__(256) void gemm_lds(
    const unsigned short* __restrict__ A,   // [M][1024] bf16 row-major
    const unsigned short* __restrict__ B,   // [LDC][1024] bf16 (nn.Linear weight rows)
    void* __restrict__ Cv) {
  constexpr int K = 1024;
  constexpr int MI = BM / 32, NI = BN / 32;

  __shared__ __align__(16) unsigned short As[BM * 64];
  __shared__ __align__(16) unsigned short Bs[BN * 64];

  const int tid = threadIdx.x;
  const int wid = tid >> 6;
  const int lane = tid & 63;
  const int quad = lane >> 4;
  const int c16 = lane & 15;
  const int wrow = wid >> 1, wcol = wid & 1;

  const int m0 = blockIdx.x * BM;   // m fastest -> same-A blocks share an XCD
  const int n0 = blockIdx.y * BN;

  f32x4 acc[MI][NI];
#pragma unroll
  for (int i = 0; i < MI; i++)
#pragma unroll
    for (int j = 0; j < NI; j++) acc[i][j] = f32x4{0.f, 0.f, 0.f, 0.f};

  for (int kb = 0; kb < K; kb += 64) {
    __syncthreads();
    stage_glds<BM, 4>(A + (size_t)m0 * K + kb, K, As, wid, lane);
    stage_glds<BN, 4>(B + (size_t)n0 * K + kb, K, Bs, wid, lane);
    __syncthreads();
#pragma unroll
    for (int ks = 0; ks < 2; ++ks) {
      bf16x8 af[MI], bfr[NI];
#pragma unroll
      for (int i = 0; i < MI; i++)
        af[i] = frag_ld(As, wrow * (BM / 2) + i * 16 + c16, ks * 4 + quad);
#pragma unroll
      for (int j = 0; j < NI; j++)
        bfr[j] = frag_ld(Bs, wcol * (BN / 2) + j * 16 + c16, ks * 4 + quad);
#pragma unroll
      for (int i = 0; i < MI; i++)
#pragma unroll
        for (int j = 0; j < NI; j++) acc[i][j] = MFMA16(af[i], bfr[j], acc[i][j]);
    }
  }

#pragma unroll
  for (int i = 0; i < MI; i++) {
#pragma unroll
    for (int j = 0; j < NI; j++) {
      int row = m0 + wrow * (BM / 2) + i * 16 + quad * 4;
      int col = n0 + wcol * (BN / 2) + j * 16 + c16;
#pragma unroll
      for (int r = 0; r < 4; r++) {
        if constexpr (CF32) ((float*)Cv)[(size_t)(row + r) * LDC + col] = acc[i][j][r];
        else ((unsigned short*)Cv)[(size_t)(row + r) * LDC + col] = f2bf(acc[i][j][r]);
      }
    }
  }
}

// =====================================================================
// QKV projection: 256x192-tile GEMM, FOUR merged phases/iteration
// (verified r11: total -3.7 µs, best config). vmcnt(3) at P34/P78.
// =====================================================================
__global__ __launch_bounds__(512) void gemm_4ph_w192(
    const unsigned short* __restrict__ A,   // [4096][1024] bf16
    const unsigned short* __restrict__ B,   // [3072][1024] bf16 (Wq|Wk|Wv rows)
    unsigned short* __restrict__ C) {       // [4096][3072] bf16
  constexpr int K = 1024;
  __shared__ __align__(16) unsigned short As[2][256 * 64];   // 32 KiB x2
  __shared__ __align__(16) unsigned short Bs[2][192 * 64];   // 24 KiB x2

  const int tid = threadIdx.x;
  const int wid = tid >> 6, lane = tid & 63;
  const int quad = lane >> 4, c16 = lane & 15;
  const int wr = wid >> 2;        // 0..1  -> 128 output rows
  const int wc = wid & 3;         // 0..3  -> 48 output cols

  const int bid = blockIdx.x;
  const int swz = (bid & 7) * 32 + (bid >> 3);
  const int m0 = (swz >> 4) * 256;
  const int n0 = (swz & 15) * 192;

  const unsigned short* Abase = A + (size_t)m0 * K;
  const unsigned short* Bbase = B + (size_t)n0 * K;

  f32x4 acc[8][3];
#pragma unroll
  for (int i = 0; i < 8; i++)
#pragma unroll
    for (int j = 0; j < 3; j++) acc[i][j] = f32x4{0.f, 0.f, 0.f, 0.f};

  bf16x8 af[4][2];   // 4 m-rows x 2 ks (both K-slices live per phase)
  bf16x8 bf0[3];     // B frags ks=0
  bf16x8 bf1[3];     // B frags ks=1

  auto lda8 = [&](const unsigned short* asb, int mo) {
#pragma unroll
    for (int mi = 0; mi < 4; mi++)
#pragma unroll
      for (int ks = 0; ks < 2; ks++)
        af[mi][ks] = frag_ld(asb, wr * 128 + (mo + mi) * 16 + c16, ks * 4 + quad);
  };
  auto ldb6 = [&](const unsigned short* bsb) {
#pragma unroll
    for (int ni = 0; ni < 3; ni++) {
      bf0[ni] = frag_ld(bsb, wc * 48 + ni * 16 + c16, quad);
      bf1[ni] = frag_ld(bsb, wc * 48 + ni * 16 + c16, 4 + quad);
    }
  };
  auto mm24 = [&](int mo) {   // 24-MFMA merged phase
    __builtin_amdgcn_s_setprio(1);
#pragma unroll
    for (int mi = 0; mi < 4; mi++)
#pragma unroll
      for (int ni = 0; ni < 3; ni++) {
        acc[mo + mi][ni] = MFMA16(af[mi][0], bf0[ni], acc[mo + mi][ni]);
        acc[mo + mi][ni] = MFMA16(af[mi][1], bf1[ni], acc[mo + mi][ni]);
      }
    __builtin_amdgcn_s_setprio(0);
  };

  // ---- prologue: B(0):3, A(0):4, B(1):3 -> vmcnt(3) leaves B(1)
  stage_glds<192, 8>(Bbase, K, Bs[0], wid, lane);
  stage_glds<128, 8>(Abase, K, As[0], wid, lane);
  stage_glds<128, 8>(Abase + (size_t)128 * K, K, As[0] + 8192, wid, lane);
  stage_glds<192, 8>(Bbase + 64, K, Bs[1], wid, lane);
  asm volatile("s_waitcnt vmcnt(3)" ::: "memory");   // tile 0 landed
  SBAR;

  for (int i = 0; i < 7; ++i) {
    const int t = 2 * i;
    const int kb1 = (t + 1) * 64, kb2 = (t + 2) * 64, kb3 = (t + 3) * 64;
    // P12: tile t mo0 (both ks); stage A(t+1) h0+h1 -> As1
    lda8(As[0], 0); ldb6(Bs[0]);
    stage_glds<128, 8>(Abase + kb1, K, As[1], wid, lane);
    stage_glds<128, 8>(Abase + (size_t)128 * K + kb1, K, As[1] + 8192, wid, lane);
    mm24(0); SBAR;
    // P34: tile t mo4; stage B(t+2)->Bs0; vmcnt(3) -> t+1 landed
    lda8(As[0], 4);
    stage_glds<192, 8>(Bbase + kb2, K, Bs[0], wid, lane);
    asm volatile("s_waitcnt vmcnt(3)" ::: "memory");
    mm24(4); SBAR;
    // P56: tile t+1 mo0; stage A(t+2)->As0
    lda8(As[1], 0); ldb6(Bs[1]);
    stage_glds<128, 8>(Abase + kb2, K, As[0], wid, lane);
    stage_glds<128, 8>(Abase + (size_t)128 * K + kb2, K, As[0] + 8192, wid, lane);
    mm24(0); SBAR;
    // P78: tile t+1 mo4; stage B(t+3)->Bs1; vmcnt(3) -> t+2 landed
    lda8(As[1], 4);
    stage_glds<192, 8>(Bbase + kb3, K, Bs[1], wid, lane);
    asm volatile("s_waitcnt vmcnt(3)" ::: "memory");
    mm24(4); SBAR;
  }

  // ---- final pair: t=14 (buf0), t=15 (buf1); stage only A(15)
  {
    const int kb1 = 15 * 64;
    lda8(As[0], 0); ldb6(Bs[0]);
    stage_glds<128, 8>(Abase + kb1, K, As[1], wid, lane);
    stage_glds<128, 8>(Abase + (size_t)128 * K + kb1, K, As[1] + 8192, wid, lane);
    mm24(0); SBAR;
    lda8(As[0], 4);
    asm volatile("s_waitcnt vmcnt(0)" ::: "memory");   // drains A(15)+B(15)
    mm24(4); SBAR;
    lda8(As[1], 0); ldb6(Bs[1]);
    mm24(0); SBAR;
    lda8(As[1], 4);
    mm24(4);
  }

#pragma unroll
  for (int mi = 0; mi < 8; mi++) {
#pragma unroll
    for (int ni = 0; ni < 3; ni++) {
      const int row = m0 + wr * 128 + mi * 16 + quad * 4;
      const int col = n0 + wc * 48 + ni * 16 + c16;
#pragma unroll
      for (int r = 0; r < 4; r++)
        C[(size_t)(row + r) * 3072 + col] = f2bf(acc[mi][ni][r]);
    }
  }
}

// =====================================================================
// Flash attention v14 (causal) — single-barrier pipeline, Vt dbuf
// (verified r7-r11: 41.3-42.8 µs). Structural floor. FROZEN.
// =====================================================================
__device__ __forceinline__ int vt_idx(int d, int kv) {
  int ck = kv >> 3;
  int s = ((d >> 3) ^ d) & 7;
  return d * 64 + ((ck ^ s) << 3) + (kv & 7);
}

struct AttnShared {
  unsigned short Kt[2][64 * 64];   // XOR-chunk swizzled K rows (8 KB x2)
  unsigned short Vt[2][64 * 64];   // vt_idx-swizzled V^T (8 KB x2)
  unsigned short Pt[4][16 * 64];   // per-wave 16x64 XOR-chunk P^T tile (8 KB)
};

__global__ __launch_bounds__(256) void attn_kernel(
    const unsigned short* __restrict__ QKV,   // [NTOK][3072]: Q | K | V (bf16)
    unsigned short* __restrict__ Oa) {        // [NTOK][1024] bf16
  __shared__ AttnShared sh;
  const int h = blockIdx.x;
  const int b = blockIdx.y;
  const int t = 31 - blockIdx.z;   // long tiles first (z is slowest dim)
  const int tid = threadIdx.x;
  const int wid = tid >> 6, lane = tid & 63;
  const int quad = lane >> 4, c16 = lane & 15;
  const size_t tokbase = (size_t)b * SEQ;
  const int q0 = t * 64;
  const int nkv = t + 1;

  // Q fragments (B-operand), scaled by 0.125 * log2(e)
  const unsigned short* qp = QKV + (tokbase + q0 + wid * 16 + c16) * 3072 + h * 64;
  bf16x8 qf[2];
#pragma unroll
  for (int ks = 0; ks < 2; ++ks) {
    u16x8 u = *(const u16x8*)(qp + ks * 32 + quad * 8);
    bf16x8 tq;
#pragma unroll
    for (int j = 0; j < 8; j++) tq[j] = (short)f2bf(0.1803368801f * bf2f(u[j]));
    qf[ks] = tq;
  }

  const unsigned short* kbase = QKV + tokbase * 3072 + 1024 + h * 64;
  const unsigned short* vbase = QKV + tokbase * 3072 + 2048 + h * 64;
  const int vkv = (tid >> 4) * 4;   // V stager: 4 kv rows
  const int vd = (tid & 15) * 4;    //           4 d cols

  f32x4 o[4];
  float lacc = 0.f;
#pragma unroll
  for (int nt = 0; nt < 4; nt++) o[nt] = f32x4{0.f, 0.f, 0.f, 0.f};
  unsigned short* PtW = sh.Pt[wid];
  const int pt_sub = (quad & 1) * 4;
  const int pt_c8h = quad >> 1;

  // ---- prologue: stage Kt[0]; load V(0) regs; write Vt[0] (pre-barrier)
  stage_glds<64, 4>(kbase, 3072, sh.Kt[0], wid, lane);
  u16x4 vr[4];
#pragma unroll
  for (int i = 0; i < 4; i++)
    vr[i] = *(const u16x4*)(vbase + (size_t)(vkv + i) * 3072 + vd);
#pragma unroll
  for (int dd = 0; dd < 4; ++dd) {   // compiler inserts vmcnt wait on vr here
    uint2 w;
    w.x = (unsigned int)vr[0][dd] | ((unsigned int)vr[1][dd] << 16);
    w.y = (unsigned int)vr[2][dd] | ((unsigned int)vr[3][dd] << 16);
    *(uint2*)&sh.Vt[0][vt_idx(vd + dd, vkv)] = w;
  }

  for (int kt = 0; kt < nkv; ++kt) {
    const int buf = kt & 1;
    // ONE barrier: publishes Vt[buf] writes (prev iter / prologue), drains
    // Kt[buf] glds (syncthreads waits vmcnt 0), frees Vt[buf^1]+Kt[buf^1].
    __syncthreads();

    const bool pf = (kt + 1 < nkv);
    if (pf) {   // issue next tile's K glds + V reg loads (fly over compute)
      const size_t nofs = (size_t)(kt + 1) * 64;
      stage_glds<64, 4>(kbase + nofs * 3072, 3072, sh.Kt[buf ^ 1], wid, lane);
#pragma unroll
      for (int i = 0; i < 4; i++)
        vr[i] = *(const u16x4*)(vbase + (nofs + vkv + i) * 3072 + vd);
    }

    // ---- S^T = K (Q*scale*log2e)^T - 16 : lane holds (kv=nt*16+quad*4+r, q=c16) ----
    const unsigned short* KtB = sh.Kt[buf];
    f32x4 st[4];
    __builtin_amdgcn_s_setprio(1);   // T5
#pragma unroll
    for (int nt = 0; nt < 4; ++nt) {
      f32x4 a = f32x4{-16.f, -16.f, -16.f, -16.f};
      a = MFMA16(frag_ld(KtB, nt * 16 + c16, quad), qf[0], a);
      a = MFMA16(frag_ld(KtB, nt * 16 + c16, 4 + quad), qf[1], a);
      st[nt] = a;
    }
    __builtin_amdgcn_s_setprio(0);
    if (kt == nkv - 1) {   // diagonal kv-tile
      const int kv0 = kt * 64;
      const int qg = q0 + wid * 16 + c16;
#pragma unroll
      for (int nt = 0; nt < 4; nt++)
#pragma unroll
        for (int r = 0; r < 4; r++) {
          int kg = kv0 + nt * 16 + quad * 4 + r;
          if (kg > qg) st[nt][r] = -1e30f;
        }
    }

    // ---- p = exp2(s); v_perm trunc-pack; XOR-chunk Pt writes ----
#pragma unroll
    for (int nt = 0; nt < 4; nt++) {
      float p0 = __builtin_amdgcn_exp2f(st[nt][0]);
      float p1 = __builtin_amdgcn_exp2f(st[nt][1]);
      float p2 = __builtin_amdgcn_exp2f(st[nt][2]);
      float p3 = __builtin_amdgcn_exp2f(st[nt][3]);
      lacc += (p0 + p1) + (p2 + p3);
      uint2 w;
      w.x = pkbf_trunc(p1, p0);
      w.y = pkbf_trunc(p3, p2);
      const int c8w = 2 * nt + pt_c8h;
      const int slot = c16 * 8 + (c8w ^ (c16 & 7));
      *(uint2*)&PtW[slot * 8 + pt_sub] = w;
    }

    if (pf) {   // write NEXT tile's V into the other Vt buffer (no barrier
                // needed before PV: PV reads Vt[buf], writes go to Vt[buf^1])
#pragma unroll
      for (int dd = 0; dd < 4; ++dd) {   // compiler vmcnt-waits on vr
        uint2 w;
        w.x = (unsigned int)vr[0][dd] | ((unsigned int)vr[1][dd] << 16);
        w.y = (unsigned int)vr[2][dd] | ((unsigned int)vr[3][dd] << 16);
        *(uint2*)&sh.Vt[buf ^ 1][vt_idx(vd + dd, vkv)] = w;
      }
    }

    // ---- O^T += V^T P^T (wave-private Pt; lgkmcnt-ordered, no barrier) ----
    const unsigned short* VtB = sh.Vt[buf];
    __builtin_amdgcn_s_setprio(1);   // T5
#pragma unroll
    for (int ks = 0; ks < 2; ++ks) {
      bf16x8 pfrag = frag_ld(PtW, c16, ks * 4 + quad);
#pragma unroll
      for (int nt2 = 0; nt2 < 4; ++nt2) {
        bf16x8 vf = *(const bf16x8*)&VtB[vt_idx(nt2 * 16 + c16, ks * 32 + quad * 8)];
        o[nt2] = MFMA16(vf, pfrag, o[nt2]);
      }
    }
    __builtin_amdgcn_s_setprio(0);
  }

  // ---- epilogue: l across quads (2 shuffles); packed dwordx2 stores ----
  lacc += __shfl_xor(lacc, 16);
  lacc += __shfl_xor(lacc, 32);
  const float linv = 1.f / lacc;
  const size_t row = tokbase + q0 + wid * 16 + c16;
#pragma unroll
  for (int nt2 = 0; nt2 < 4; nt2++) {
    uint2 w;
    w.x = (unsigned int)f2bf(o[nt2][0] * linv) | ((unsigned int)f2bf(o[nt2][1] * linv) << 16);
    w.y = (unsigned int)f2bf(o[nt2][2] * linv) | ((unsigned int)f2bf(o[nt2][3] * linv) << 16);
    *(uint2*)&Oa[row * 1024 + h * 64 + nt2 * 16 + quad * 4] = w;
  }
}

// =====================================================================
// Round-2 fallback GEMM (fp32 staging) — used only if ws_size < 40 MB.
// =====================================================================
template <int BM, int BN, int LDC, bool AF32, bool CF32>
__global__ __launch_bounds__(256) void gemm_bt(
    const void* __restrict__ Av, const float* __restrict__ W0, const float* __restrict__ W1,
    const float* __restrict__ W2, void* __restrict__ Cv) {
  constexpr int K = 1024;
  constexpr int LDS_LD = 72;
  constexpr int MI = BM / 32, NI = BN / 32;
  __shared__ __align__(16) unsigned short As[BM][LDS_LD];
  __shared__ __align__(16) unsigned short Bs[BN][LDS_LD];
  const int tid = threadIdx.x, wid = tid >> 6, lane = tid & 63;
  const int quad = lane >> 4, c16 = lane & 15;
  const int wrow = wid >> 1, wcol = wid & 1;
  const float* W = (blockIdx.z == 0) ? W0 : (blockIdx.z == 1 ? W1 : W2);
  const int m0 = blockIdx.y * BM, n0 = blockIdx.x * BN, cofs = blockIdx.z * 1024;
  f32x4 acc[MI][NI];
#pragma unroll
  for (int i = 0; i < MI; i++)
#pragma unroll
    for (int j = 0; j < NI; j++) acc[i][j] = f32x4{0.f, 0.f, 0.f, 0.f};
  for (int kb = 0; kb < K; kb += 64) {
    __syncthreads();
#pragma unroll
    for (int c = tid; c < BM * 8; c += 256) {
      int row = c >> 3, c8 = c & 7;
      if constexpr (AF32)
        *(u16x8*)&As[row][c8 * 8] = cvt8((const float*)Av + (size_t)(m0 + row) * K + kb + c8 * 8);
      else
        *(u16x8*)&As[row][c8 * 8] = *(const u16x8*)((const unsigned short*)Av + (size_t)(m0 + row) * K + kb + c8 * 8);
    }
#pragma unroll
    for (int c = tid; c < BN * 8; c += 256) {
      int row = c >> 3, c8 = c & 7;
      *(u16x8*)&Bs[row][c8 * 8] = cvt8(W + (size_t)(n0 + row) * K + kb + c8 * 8);
    }
    __syncthreads();
#pragma unroll
    for (int ks = 0; ks < 2; ++ks) {
      bf16x8 af[MI], bfr[NI];
#pragma unroll
      for (int i = 0; i < MI; i++)
        af[i] = *(const bf16x8*)&As[wrow * (BM / 2) + i * 16 + c16][ks * 32 + quad * 8];
#pragma unroll
      for (int j = 0; j < NI; j++)
        bfr[j] = *(const bf16x8*)&Bs[wcol * (BN / 2) + j * 16 + c16][ks * 32 + quad * 8];
#pragma unroll
      for (int i = 0; i < MI; i++)
#pragma unroll
        for (int j = 0; j < NI; j++) acc[i][j] = MFMA16(af[i], bfr[j], acc[i][j]);
    }
  }
#pragma unroll
  for (int i = 0; i < MI; i++)
#pragma unroll
    for (int j = 0; j < NI; j++) {
      int row = m0 + wrow * (BM / 2) + i * 16 + quad * 4;
      int col = n0 + wcol * (BN / 2) + j * 16 + c16 + cofs;
#pragma unroll
      for (int r = 0; r < 4; r++) {
        if constexpr (CF32) ((float*)Cv)[(size_t)(row + r) * LDC + col] = acc[i][j][r];
        else ((unsigned short*)Cv)[(size_t)(row + r) * LDC + col] = f2bf(acc[i][j][r]);
      }
    }
}

// =====================================================================
extern "C" void kernel_launch(void* const* d_in, const int* in_sizes, int n_in,
                              void* d_out, int out_size, void* d_ws, size_t ws_size,
                              hipStream_t stream) {
  const float* x = (const float*)d_in[0];
  const float* Wq = (const float*)d_in[2];
  const float* Wk = (const float*)d_in[3];
  const float* Wv = (const float*)d_in[4];
  const float* Wo = (const float*)d_in[5];
  float* out = (float*)d_out;

  unsigned short* QKV = (unsigned short*)d_ws;                 // [4096][3072] bf16 (24MB)
  unsigned short* Wb = QKV + (size_t)NTOK * 3072;              // 4 x [1024][1024] bf16 (8MB)
  unsigned short* Xb = Wb + (size_t)4 * 1024 * 1024;           // [4096][1024] bf16 (8MB), == AT
  unsigned short* AT = Xb;

  if (ws_size >= (size_t)40 * 1024 * 1024) {
    // convert: flat balanced grid (2048 blocks, 2 iters/thread exactly)
    cvt_all<<<dim3(2048), 256, 0, stream>>>(x, Wq, Wk, Wv, Wo, Xb, Wb);
    // fused QKV projection: 256x192, FOUR merged phases (r11, best)
    gemm_4ph_w192<<<dim3(256), 512, 0, stream>>>(Xb, Wb, QKV);
    // flash attention v14: single-barrier pipeline, Vt double-buffer
    attn_kernel<<<dim3(NH, 2, 32), 256, 0, stream>>>(QKV, AT);
    // output projection: r11-proven gemm_lds 128x64 (r12 rewrite reverted)
    gemm_lds<128, 64, 1024, true><<<dim3(32, 16), 256, 0, stream>>>(
        AT, Wb + (size_t)3 * 1024 * 1024, out);
  } else {
    unsigned short* QKV2 = (unsigned short*)d_ws;
    unsigned short* AT2 = QKV2 + (size_t)NTOK * 3072;
    gemm_bt<128, 128, 3072, true, false><<<dim3(8, 32, 3), 256, 0, stream>>>(x, Wq, Wk, Wv, QKV2);
    attn_kernel<<<dim3(NH, 2, 32), 256, 0, stream>>>(QKV2, AT2);
    gemm_bt<64, 64, 1024, false, true><<<dim3(16, 64, 1), 256, 0, stream>>>(AT2, Wo, Wo, Wo, out);
  }
}

// Round 14
// 171.136 us; speedup vs baseline: 1.0234x; 1.0025x over previous
//
#include <hip/hip_runtime.h>
#include <hip/hip_bf16.h>

// ---- types ----
typedef short bf16x8 __attribute__((ext_vector_type(8)));          // 8 bf16 = 4 VGPRs (MFMA A/B frag)
typedef unsigned short u16x8 __attribute__((ext_vector_type(8)));
typedef unsigned short u16x4 __attribute__((ext_vector_type(4)));
typedef float f32x4 __attribute__((ext_vector_type(4)));           // MFMA C/D frag

typedef unsigned int __attribute__((address_space(1))) gu32;       // global
typedef unsigned int __attribute__((address_space(3))) lu32;       // LDS

#define MFMA16(a, b, c) __builtin_amdgcn_mfma_f32_16x16x32_bf16((a), (b), (c), 0, 0, 0)

constexpr int SEQ = 2048;
constexpr int NH = 16;
constexpr int NTOK = 2 * SEQ;  // 4096

__device__ __forceinline__ float bf2f(unsigned short u) {
  union { unsigned int i; float f; } v; v.i = ((unsigned int)u) << 16; return v.f;
}
__device__ __forceinline__ unsigned short f2bf(float f) {
  __hip_bfloat16 h = __float2bfloat16(f);   // RNE
  return __builtin_bit_cast(unsigned short, h);
}
// pack two fp32 -> bf16 pair by TRUNCATION via one v_perm_b32 (hi<<16 | lo)
__device__ __forceinline__ unsigned int pkbf_trunc(float hi, float lo) {
  return __builtin_amdgcn_perm(__builtin_bit_cast(unsigned int, hi),
                               __builtin_bit_cast(unsigned int, lo), 0x07060302u);
}
__device__ __forceinline__ u16x8 cvt8(const float* __restrict__ p) {
  f32x4 a = *(const f32x4*)p;
  f32x4 b = *(const f32x4*)(p + 4);
  u16x8 r;
#pragma unroll
  for (int j = 0; j < 4; j++) { r[j] = f2bf(a[j]); r[4 + j] = f2bf(b[j]); }
  return r;
}

// =====================================================================
// Convert pass v2: flat balanced 1-D grid (r10).
// =====================================================================
__global__ __launch_bounds__(256) void cvt_all(
    const float* __restrict__ x, const float* __restrict__ wq, const float* __restrict__ wk,
    const float* __restrict__ wv, const float* __restrict__ wo,
    unsigned short* __restrict__ Xb, unsigned short* __restrict__ Wb) {
  const size_t XN = (size_t)NTOK * 1024;        // 4M
  const size_t TOT = XN + (size_t)4 * 1024 * 1024;  // 8M
  for (size_t i = ((size_t)blockIdx.x * 256 + threadIdx.x) * 8; i < TOT;
       i += (size_t)gridDim.x * 256 * 8) {
    if (i < XN) {
      *(u16x8*)(Xb + i) = cvt8(x + i);
    } else {
      const size_t j = i - XN;
      const int w = (int)(j >> 20);   // which 1M-elem weight
      const float* src = (w == 0) ? wq : (w == 1) ? wk : (w == 2) ? wv : wo;
      *(u16x8*)(Wb + j) = cvt8(src + (j & (((size_t)1 << 20) - 1)));
    }
  }
}

// =====================================================================
// Async global->LDS staging with XOR-chunk permutation (verified r3):
// 16B chunk (row, c8) -> slot row*8 + (c8 ^ (row&7)).
// =====================================================================
template <int ROWS, int NWAVE>
__device__ __forceinline__ void stage_glds(const unsigned short* __restrict__ gbase,
                                           int rstride,
                                           unsigned short* __restrict__ lds,
                                           int wid, int lane) {
  constexpr int ISS = ROWS * 8 / (NWAVE * 64);
#pragma unroll
  for (int t = 0; t < ISS; ++t) {
    const int slot = (wid * ISS + t) * 64 + lane;
    const int row = slot >> 3;
    const int c8 = (slot & 7) ^ (row & 7);
    const unsigned short* gp = gbase + (size_t)row * rstride + c8 * 8;
    unsigned short* lp = lds + (size_t)(wid * ISS + t) * 512;   // wave-uniform, 1 KiB/issue
    __builtin_amdgcn_global_load_lds((const gu32*)gp, (lu32*)lp, 16, 0, 0);
  }
}

__device__ __forceinline__ bf16x8 frag_ld(const unsigned short* __restrict__ lds, int row, int c8) {
  const int slot = row * 8 + (c8 ^ (row & 7));
  return *(const bf16x8*)(lds + slot * 8);
}

#define SBAR do { __builtin_amdgcn_sched_barrier(0); \
                  asm volatile("s_barrier" ::: "memory"); \
                  __builtin_amdgcn_sched_barrier(0); } while (0)

// =====================================================================
// Output projection r14: gemm_lds structure (PROVEN: sync -> burst
// stage -> sync -> compute; r9/r12 sync-structure rewrites both
// regressed) with BK=128 — barrier amortization only, the lever class
// that won in r8 and r11. 8 iterations x 2 barriers = 16 (was 32).
// Same 20 glds issues/wave/iter; identical FP accumulation order
// (ascending K). LDS 48 KB; occupancy grid-capped at 2 blocks/CU so
// no occupancy cost (m132 caveat n/a).
// =====================================================================
__global__ __launch_bounds__(256) void gemm_op_bk128(
    const unsigned short* __restrict__ A,   // [4096][1024] bf16 (attn out)
    const unsigned short* __restrict__ B,   // [1024][1024] bf16 (Wo rows)
    float* __restrict__ C) {                // [4096][1024] fp32
  constexpr int K = 1024;
  constexpr int MI = 4, NI = 2;
  __shared__ __align__(16) unsigned short As[2][128 * 64];   // 16 KiB x2 (half-K regions)
  __shared__ __align__(16) unsigned short Bs[2][64 * 64];    // 8 KiB x2

  const int tid = threadIdx.x;
  const int wid = tid >> 6;
  const int lane = tid & 63;
  const int quad = lane >> 4;
  const int c16 = lane & 15;
  const int wrow = wid >> 1, wcol = wid & 1;

  const int m0 = blockIdx.x * 128;   // m fastest -> same-A blocks share an XCD
  const int n0 = blockIdx.y * 64;

  f32x4 acc[MI][NI];
#pragma unroll
  for (int i = 0; i < MI; i++)
#pragma unroll
    for (int j = 0; j < NI; j++) acc[i][j] = f32x4{0.f, 0.f, 0.f, 0.f};

  for (int kb = 0; kb < K; kb += 128) {
    __syncthreads();
    stage_glds<128, 4>(A + (size_t)m0 * K + kb, K, As[0], wid, lane);
    stage_glds<128, 4>(A + (size_t)m0 * K + kb + 64, K, As[1], wid, lane);
    stage_glds<64, 4>(B + (size_t)n0 * K + kb, K, Bs[0], wid, lane);
    stage_glds<64, 4>(B + (size_t)n0 * K + kb + 64, K, Bs[1], wid, lane);
    __syncthreads();
#pragma unroll
    for (int ks = 0; ks < 4; ++ks) {
      const unsigned short* Asr = As[ks >> 1];
      const unsigned short* Bsr = Bs[ks >> 1];
      const int c8 = (ks & 1) * 4 + quad;
      bf16x8 af[MI], bfr[NI];
#pragma unroll
      for (int i = 0; i < MI; i++)
        af[i] = frag_ld(Asr, wrow * 64 + i * 16 + c16, c8);
#pragma unroll
      for (int j = 0; j < NI; j++)
        bfr[j] = frag_ld(Bsr, wcol * 32 + j * 16 + c16, c8);
#pragma unroll
      for (int i = 0; i < MI; i++)
#pragma unroll
        for (int j = 0; j < NI; j++) acc[i][j] = MFMA16(af[i], bfr[j], acc[i][j]);
    }
  }

#pragma unroll
  for (int i = 0; i < MI; i++) {
#pragma unroll
    for (int j = 0; j < NI; j++) {
      const int row = m0 + wrow * 64 + i * 16 + quad * 4;
      const int col = n0 + wcol * 32 + j * 16 + c16;
#pragma unroll
      for (int r = 0; r < 4; r++)
        C[(size_t)(row + r) * 1024 + col] = acc[i][j][r];
    }
  }
}

// =====================================================================
// QKV projection: 256x192-tile GEMM, FOUR merged phases/iteration
// (verified r11/r13: best config). vmcnt(3) at P34/P78. FROZEN
// (merging further to 2 phases breaks 2-buffer region safety:
// B(t+2) would overwrite Bs[0] in the same phase that reads it).
// =====================================================================
__global__ __launch_bounds__(512) void gemm_4ph_w192(
    const unsigned short* __restrict__ A,   // [4096][1024] bf16
    const unsigned short* __restrict__ B,   // [3072][1024] bf16 (Wq|Wk|Wv rows)
    unsigned short* __restrict__ C) {       // [4096][3072] bf16
  constexpr int K = 1024;
  __shared__ __align__(16) unsigned short As[2][256 * 64];   // 32 KiB x2
  __shared__ __align__(16) unsigned short Bs[2][192 * 64];   // 24 KiB x2

  const int tid = threadIdx.x;
  const int wid = tid >> 6, lane = tid & 63;
  const int quad = lane >> 4, c16 = lane & 15;
  const int wr = wid >> 2;        // 0..1  -> 128 output rows
  const int wc = wid & 3;         // 0..3  -> 48 output cols

  const int bid = blockIdx.x;
  const int swz = (bid & 7) * 32 + (bid >> 3);
  const int m0 = (swz >> 4) * 256;
  const int n0 = (swz & 15) * 192;

  const unsigned short* Abase = A + (size_t)m0 * K;
  const unsigned short* Bbase = B + (size_t)n0 * K;

  f32x4 acc[8][3];
#pragma unroll
  for (int i = 0; i < 8; i++)
#pragma unroll
    for (int j = 0; j < 3; j++) acc[i][j] = f32x4{0.f, 0.f, 0.f, 0.f};

  bf16x8 af[4][2];   // 4 m-rows x 2 ks (both K-slices live per phase)
  bf16x8 bf0[3];     // B frags ks=0
  bf16x8 bf1[3];     // B frags ks=1

  auto lda8 = [&](const unsigned short* asb, int mo) {
#pragma unroll
    for (int mi = 0; mi < 4; mi++)
#pragma unroll
      for (int ks = 0; ks < 2; ks++)
        af[mi][ks] = frag_ld(asb, wr * 128 + (mo + mi) * 16 + c16, ks * 4 + quad);
  };
  auto ldb6 = [&](const unsigned short* bsb) {
#pragma unroll
    for (int ni = 0; ni < 3; ni++) {
      bf0[ni] = frag_ld(bsb, wc * 48 + ni * 16 + c16, quad);
      bf1[ni] = frag_ld(bsb, wc * 48 + ni * 16 + c16, 4 + quad);
    }
  };
  auto mm24 = [&](int mo) {   // 24-MFMA merged phase
    __builtin_amdgcn_s_setprio(1);
#pragma unroll
    for (int mi = 0; mi < 4; mi++)
#pragma unroll
      for (int ni = 0; ni < 3; ni++) {
        acc[mo + mi][ni] = MFMA16(af[mi][0], bf0[ni], acc[mo + mi][ni]);
        acc[mo + mi][ni] = MFMA16(af[mi][1], bf1[ni], acc[mo + mi][ni]);
      }
    __builtin_amdgcn_s_setprio(0);
  };

  // ---- prologue: B(0):3, A(0):4, B(1):3 -> vmcnt(3) leaves B(1)
  stage_glds<192, 8>(Bbase, K, Bs[0], wid, lane);
  stage_glds<128, 8>(Abase, K, As[0], wid, lane);
  stage_glds<128, 8>(Abase + (size_t)128 * K, K, As[0] + 8192, wid, lane);
  stage_glds<192, 8>(Bbase + 64, K, Bs[1], wid, lane);
  asm volatile("s_waitcnt vmcnt(3)" ::: "memory");   // tile 0 landed
  SBAR;

  for (int i = 0; i < 7; ++i) {
    const int t = 2 * i;
    const int kb1 = (t + 1) * 64, kb2 = (t + 2) * 64, kb3 = (t + 3) * 64;
    // P12: tile t mo0 (both ks); stage A(t+1) h0+h1 -> As1
    lda8(As[0], 0); ldb6(Bs[0]);
    stage_glds<128, 8>(Abase + kb1, K, As[1], wid, lane);
    stage_glds<128, 8>(Abase + (size_t)128 * K + kb1, K, As[1] + 8192, wid, lane);
    mm24(0); SBAR;
    // P34: tile t mo4; stage B(t+2)->Bs0; vmcnt(3) -> t+1 landed
    lda8(As[0], 4);
    stage_glds<192, 8>(Bbase + kb2, K, Bs[0], wid, lane);
    asm volatile("s_waitcnt vmcnt(3)" ::: "memory");
    mm24(4); SBAR;
    // P56: tile t+1 mo0; stage A(t+2)->As0
    lda8(As[1], 0); ldb6(Bs[1]);
    stage_glds<128, 8>(Abase + kb2, K, As[0], wid, lane);
    stage_glds<128, 8>(Abase + (size_t)128 * K + kb2, K, As[0] + 8192, wid, lane);
    mm24(0); SBAR;
    // P78: tile t+1 mo4; stage B(t+3)->Bs1; vmcnt(3) -> t+2 landed
    lda8(As[1], 4);
    stage_glds<192, 8>(Bbase + kb3, K, Bs[1], wid, lane);
    asm volatile("s_waitcnt vmcnt(3)" ::: "memory");
    mm24(4); SBAR;
  }

  // ---- final pair: t=14 (buf0), t=15 (buf1); stage only A(15)
  {
    const int kb1 = 15 * 64;
    lda8(As[0], 0); ldb6(Bs[0]);
    stage_glds<128, 8>(Abase + kb1, K, As[1], wid, lane);
    stage_glds<128, 8>(Abase + (size_t)128 * K + kb1, K, As[1] + 8192, wid, lane);
    mm24(0); SBAR;
    lda8(As[0], 4);
    asm volatile("s_waitcnt vmcnt(0)" ::: "memory");   // drains A(15)+B(15)
    mm24(4); SBAR;
    lda8(As[1], 0); ldb6(Bs[1]);
    mm24(0); SBAR;
    lda8(As[1], 4);
    mm24(4);
  }

#pragma unroll
  for (int mi = 0; mi < 8; mi++) {
#pragma unroll
    for (int ni = 0; ni < 3; ni++) {
      const int row = m0 + wr * 128 + mi * 16 + quad * 4;
      const int col = n0 + wc * 48 + ni * 16 + c16;
#pragma unroll
      for (int r = 0; r < 4; r++)
        C[(size_t)(row + r) * 3072 + col] = f2bf(acc[mi][ni][r]);
    }
  }
}

// =====================================================================
// Flash attention v14 (causal) — single-barrier pipeline, Vt dbuf
// (verified r7-r13: 41.3-43.2 µs). Structural floor. FROZEN.
// =====================================================================
__device__ __forceinline__ int vt_idx(int d, int kv) {
  int ck = kv >> 3;
  int s = ((d >> 3) ^ d) & 7;
  return d * 64 + ((ck ^ s) << 3) + (kv & 7);
}

struct AttnShared {
  unsigned short Kt[2][64 * 64];   // XOR-chunk swizzled K rows (8 KB x2)
  unsigned short Vt[2][64 * 64];   // vt_idx-swizzled V^T (8 KB x2)
  unsigned short Pt[4][16 * 64];   // per-wave 16x64 XOR-chunk P^T tile (8 KB)
};

__global__ __launch_bounds__(256) void attn_kernel(
    const unsigned short* __restrict__ QKV,   // [NTOK][3072]: Q | K | V (bf16)
    unsigned short* __restrict__ Oa) {        // [NTOK][1024] bf16
  __shared__ AttnShared sh;
  const int h = blockIdx.x;
  const int b = blockIdx.y;
  const int t = 31 - blockIdx.z;   // long tiles first (z is slowest dim)
  const int tid = threadIdx.x;
  const int wid = tid >> 6, lane = tid & 63;
  const int quad = lane >> 4, c16 = lane & 15;
  const size_t tokbase = (size_t)b * SEQ;
  const int q0 = t * 64;
  const int nkv = t + 1;

  // Q fragments (B-operand), scaled by 0.125 * log2(e)
  const unsigned short* qp = QKV + (tokbase + q0 + wid * 16 + c16) * 3072 + h * 64;
  bf16x8 qf[2];
#pragma unroll
  for (int ks = 0; ks < 2; ++ks) {
    u16x8 u = *(const u16x8*)(qp + ks * 32 + quad * 8);
    bf16x8 tq;
#pragma unroll
    for (int j = 0; j < 8; j++) tq[j] = (short)f2bf(0.1803368801f * bf2f(u[j]));
    qf[ks] = tq;
  }

  const unsigned short* kbase = QKV + tokbase * 3072 + 1024 + h * 64;
  const unsigned short* vbase = QKV + tokbase * 3072 + 2048 + h * 64;
  const int vkv = (tid >> 4) * 4;   // V stager: 4 kv rows
  const int vd = (tid & 15) * 4;    //           4 d cols

  f32x4 o[4];
  float lacc = 0.f;
#pragma unroll
  for (int nt = 0; nt < 4; nt++) o[nt] = f32x4{0.f, 0.f, 0.f, 0.f};
  unsigned short* PtW = sh.Pt[wid];
  const int pt_sub = (quad & 1) * 4;
  const int pt_c8h = quad >> 1;

  // ---- prologue: stage Kt[0]; load V(0) regs; write Vt[0] (pre-barrier)
  stage_glds<64, 4>(kbase, 3072, sh.Kt[0], wid, lane);
  u16x4 vr[4];
#pragma unroll
  for (int i = 0; i < 4; i++)
    vr[i] = *(const u16x4*)(vbase + (size_t)(vkv + i) * 3072 + vd);
#pragma unroll
  for (int dd = 0; dd < 4; ++dd) {   // compiler inserts vmcnt wait on vr here
    uint2 w;
    w.x = (unsigned int)vr[0][dd] | ((unsigned int)vr[1][dd] << 16);
    w.y = (unsigned int)vr[2][dd] | ((unsigned int)vr[3][dd] << 16);
    *(uint2*)&sh.Vt[0][vt_idx(vd + dd, vkv)] = w;
  }

  for (int kt = 0; kt < nkv; ++kt) {
    const int buf = kt & 1;
    // ONE barrier: publishes Vt[buf] writes (prev iter / prologue), drains
    // Kt[buf] glds (syncthreads waits vmcnt 0), frees Vt[buf^1]+Kt[buf^1].
    __syncthreads();

    const bool pf = (kt + 1 < nkv);
    if (pf) {   // issue next tile's K glds + V reg loads (fly over compute)
      const size_t nofs = (size_t)(kt + 1) * 64;
      stage_glds<64, 4>(kbase + nofs * 3072, 3072, sh.Kt[buf ^ 1], wid, lane);
#pragma unroll
      for (int i = 0; i < 4; i++)
        vr[i] = *(const u16x4*)(vbase + (nofs + vkv + i) * 3072 + vd);
    }

    // ---- S^T = K (Q*scale*log2e)^T - 16 : lane holds (kv=nt*16+quad*4+r, q=c16) ----
    const unsigned short* KtB = sh.Kt[buf];
    f32x4 st[4];
    __builtin_amdgcn_s_setprio(1);   // T5
#pragma unroll
    for (int nt = 0; nt < 4; ++nt) {
      f32x4 a = f32x4{-16.f, -16.f, -16.f, -16.f};
      a = MFMA16(frag_ld(KtB, nt * 16 + c16, quad), qf[0], a);
      a = MFMA16(frag_ld(KtB, nt * 16 + c16, 4 + quad), qf[1], a);
      st[nt] = a;
    }
    __builtin_amdgcn_s_setprio(0);
    if (kt == nkv - 1) {   // diagonal kv-tile
      const int kv0 = kt * 64;
      const int qg = q0 + wid * 16 + c16;
#pragma unroll
      for (int nt = 0; nt < 4; nt++)
#pragma unroll
        for (int r = 0; r < 4; r++) {
          int kg = kv0 + nt * 16 + quad * 4 + r;
          if (kg > qg) st[nt][r] = -1e30f;
        }
    }

    // ---- p = exp2(s); v_perm trunc-pack; XOR-chunk Pt writes ----
#pragma unroll
    for (int nt = 0; nt < 4; nt++) {
      float p0 = __builtin_amdgcn_exp2f(st[nt][0]);
      float p1 = __builtin_amdgcn_exp2f(st[nt][1]);
      float p2 = __builtin_amdgcn_exp2f(st[nt][2]);
      float p3 = __builtin_amdgcn_exp2f(st[nt][3]);
      lacc += (p0 + p1) + (p2 + p3);
      uint2 w;
      w.x = pkbf_trunc(p1, p0);
      w.y = pkbf_trunc(p3, p2);
      const int c8w = 2 * nt + pt_c8h;
      const int slot = c16 * 8 + (c8w ^ (c16 & 7));
      *(uint2*)&PtW[slot * 8 + pt_sub] = w;
    }

    if (pf) {   // write NEXT tile's V into the other Vt buffer (no barrier
                // needed before PV: PV reads Vt[buf], writes go to Vt[buf^1])
#pragma unroll
      for (int dd = 0; dd < 4; ++dd) {   // compiler vmcnt-waits on vr
        uint2 w;
        w.x = (unsigned int)vr[0][dd] | ((unsigned int)vr[1][dd] << 16);
        w.y = (unsigned int)vr[2][dd] | ((unsigned int)vr[3][dd] << 16);
        *(uint2*)&sh.Vt[buf ^ 1][vt_idx(vd + dd, vkv)] = w;
      }
    }

    // ---- O^T += V^T P^T (wave-private Pt; lgkmcnt-ordered, no barrier) ----
    const unsigned short* VtB = sh.Vt[buf];
    __builtin_amdgcn_s_setprio(1);   // T5
#pragma unroll
    for (int ks = 0; ks < 2; ++ks) {
      bf16x8 pfrag = frag_ld(PtW, c16, ks * 4 + quad);
#pragma unroll
      for (int nt2 = 0; nt2 < 4; ++nt2) {
        bf16x8 vf = *(const bf16x8*)&VtB[vt_idx(nt2 * 16 + c16, ks * 32 + quad * 8)];
        o[nt2] = MFMA16(vf, pfrag, o[nt2]);
      }
    }
    __builtin_amdgcn_s_setprio(0);
  }

  // ---- epilogue: l across quads (2 shuffles); packed dwordx2 stores ----
  lacc += __shfl_xor(lacc, 16);
  lacc += __shfl_xor(lacc, 32);
  const float linv = 1.f / lacc;
  const size_t row = tokbase + q0 + wid * 16 + c16;
#pragma unroll
  for (int nt2 = 0; nt2 < 4; nt2++) {
    uint2 w;
    w.x = (unsigned int)f2bf(o[nt2][0] * linv) | ((unsigned int)f2bf(o[nt2][1] * linv) << 16);
    w.y = (unsigned int)f2bf(o[nt2][2] * linv) | ((unsigned int)f2bf(o[nt2][3] * linv) << 16);
    *(uint2*)&Oa[row * 1024 + h * 64 + nt2 * 16 + quad * 4] = w;
  }
}

// =====================================================================
// Round-2 fallback GEMM (fp32 staging) — used only if ws_size < 40 MB.
// =====================================================================
template <int BM, int BN, int LDC, bool AF32, bool CF32>
__global__ __launch_bounds__(256) void gemm_bt(
    const void* __restrict__ Av, const float* __restrict__ W0, const float* __restrict__ W1,
    const float* __restrict__ W2, void* __restrict__ Cv) {
  constexpr int K = 1024;
  constexpr int LDS_LD = 72;
  constexpr int MI = BM / 32, NI = BN / 32;
  __shared__ __align__(16) unsigned short As[BM][LDS_LD];
  __shared__ __align__(16) unsigned short Bs[BN][LDS_LD];
  const int tid = threadIdx.x, wid = tid >> 6, lane = tid & 63;
  const int quad = lane >> 4, c16 = lane & 15;
  const int wrow = wid >> 1, wcol = wid & 1;
  const float* W = (blockIdx.z == 0) ? W0 : (blockIdx.z == 1 ? W1 : W2);
  const int m0 = blockIdx.y * BM, n0 = blockIdx.x * BN, cofs = blockIdx.z * 1024;
  f32x4 acc[MI][NI];
#pragma unroll
  for (int i = 0; i < MI; i++)
#pragma unroll
    for (int j = 0; j < NI; j++) acc[i][j] = f32x4{0.f, 0.f, 0.f, 0.f};
  for (int kb = 0; kb < K; kb += 64) {
    __syncthreads();
#pragma unroll
    for (int c = tid; c < BM * 8; c += 256) {
      int row = c >> 3, c8 = c & 7;
      if constexpr (AF32)
        *(u16x8*)&As[row][c8 * 8] = cvt8((const float*)Av + (size_t)(m0 + row) * K + kb + c8 * 8);
      else
        *(u16x8*)&As[row][c8 * 8] = *(const u16x8*)((const unsigned short*)Av + (size_t)(m0 + row) * K + kb + c8 * 8);
    }
#pragma unroll
    for (int c = tid; c < BN * 8; c += 256) {
      int row = c >> 3, c8 = c & 7;
      *(u16x8*)&Bs[row][c8 * 8] = cvt8(W + (size_t)(n0 + row) * K + kb + c8 * 8);
    }
    __syncthreads();
#pragma unroll
    for (int ks = 0; ks < 2; ++ks) {
      bf16x8 af[MI], bfr[NI];
#pragma unroll
      for (int i = 0; i < MI; i++)
        af[i] = *(const bf16x8*)&As[wrow * (BM / 2) + i * 16 + c16][ks * 32 + quad * 8];
#pragma unroll
      for (int j = 0; j < NI; j++)
        bfr[j] = *(const bf16x8*)&Bs[wcol * (BN / 2) + j * 16 + c16][ks * 32 + quad * 8];
#pragma unroll
      for (int i = 0; i < MI; i++)
#pragma unroll
        for (int j = 0; j < NI; j++) acc[i][j] = MFMA16(af[i], bfr[j], acc[i][j]);
    }
  }
#pragma unroll
  for (int i = 0; i < MI; i++)
#pragma unroll
    for (int j = 0; j < NI; j++) {
      int row = m0 + wrow * (BM / 2) + i * 16 + quad * 4;
      int col = n0 + wcol * (BN / 2) + j * 16 + c16 + cofs;
#pragma unroll
      for (int r = 0; r < 4; r++) {
        if constexpr (CF32) ((float*)Cv)[(size_t)(row + r) * LDC + col] = acc[i][j][r];
        else ((unsigned short*)Cv)[(size_t)(row + r) * LDC + col] = f2bf(acc[i][j][r]);
      }
    }
}

// =====================================================================
extern "C" void kernel_launch(void* const* d_in, const int* in_sizes, int n_in,
                              void* d_out, int out_size, void* d_ws, size_t ws_size,
                              hipStream_t stream) {
  const float* x = (const float*)d_in[0];
  const float* Wq = (const float*)d_in[2];
  const float* Wk = (const float*)d_in[3];
  const float* Wv = (const float*)d_in[4];
  const float* Wo = (const float*)d_in[5];
  float* out = (float*)d_out;

  unsigned short* QKV = (unsigned short*)d_ws;                 // [4096][3072] bf16 (24MB)
  unsigned short* Wb = QKV + (size_t)NTOK * 3072;              // 4 x [1024][1024] bf16 (8MB)
  unsigned short* Xb = Wb + (size_t)4 * 1024 * 1024;           // [4096][1024] bf16 (8MB), == AT
  unsigned short* AT = Xb;

  if (ws_size >= (size_t)40 * 1024 * 1024) {
    // convert: flat balanced grid (2048 blocks, 2 iters/thread exactly)
    cvt_all<<<dim3(2048), 256, 0, stream>>>(x, Wq, Wk, Wv, Wo, Xb, Wb);
    // fused QKV projection: 256x192, FOUR merged phases (r11, best)
    gemm_4ph_w192<<<dim3(256), 512, 0, stream>>>(Xb, Wb, QKV);
    // flash attention v14: single-barrier pipeline, Vt double-buffer
    attn_kernel<<<dim3(NH, 2, 32), 256, 0, stream>>>(QKV, AT);
    // output projection: gemm_lds structure with BK=128 (r14: 16 barriers)
    gemm_op_bk128<<<dim3(32, 16), 256, 0, stream>>>(
        AT, Wb + (size_t)3 * 1024 * 1024, out);
  } else {
    unsigned short* QKV2 = (unsigned short*)d_ws;
    unsigned short* AT2 = QKV2 + (size_t)NTOK * 3072;
    gemm_bt<128, 128, 3072, true, false><<<dim3(8, 32, 3), 256, 0, stream>>>(x, Wq, Wk, Wv, QKV2);
    attn_kernel<<<dim3(NH, 2, 32), 256, 0, stream>>>(QKV2, AT2);
    gemm_bt<64, 64, 1024, false, true><<<dim3(16, 64, 1), 256, 0, stream>>>(AT2, Wo, Wo, Wo, out);
  }
}

// Round 15
// 168.493 us; speedup vs baseline: 1.0395x; 1.0157x over previous
//
#include <hip/hip_runtime.h>
#include <hip/hip_bf16.h>

// ---- types ----
typedef short bf16x8 __attribute__((ext_vector_type(8)));          // 8 bf16 = 4 VGPRs (MFMA A/B frag)
typedef unsigned short u16x8 __attribute__((ext_vector_type(8)));
typedef unsigned short u16x4 __attribute__((ext_vector_type(4)));
typedef float f32x4 __attribute__((ext_vector_type(4)));           // MFMA C/D frag

typedef unsigned int __attribute__((address_space(1))) gu32;       // global
typedef unsigned int __attribute__((address_space(3))) lu32;       // LDS

#define MFMA16(a, b, c) __builtin_amdgcn_mfma_f32_16x16x32_bf16((a), (b), (c), 0, 0, 0)

constexpr int SEQ = 2048;
constexpr int NH = 16;
constexpr int NTOK = 2 * SEQ;  // 4096

__device__ __forceinline__ float bf2f(unsigned short u) {
  union { unsigned int i; float f; } v; v.i = ((unsigned int)u) << 16; return v.f;
}
__device__ __forceinline__ unsigned short f2bf(float f) {
  __hip_bfloat16 h = __float2bfloat16(f);   // RNE
  return __builtin_bit_cast(unsigned short, h);
}
// pack two fp32 -> bf16 pair by TRUNCATION via one v_perm_b32 (hi<<16 | lo)
__device__ __forceinline__ unsigned int pkbf_trunc(float hi, float lo) {
  return __builtin_amdgcn_perm(__builtin_bit_cast(unsigned int, hi),
                               __builtin_bit_cast(unsigned int, lo), 0x07060302u);
}
__device__ __forceinline__ u16x8 cvt8(const float* __restrict__ p) {
  f32x4 a = *(const f32x4*)p;
  f32x4 b = *(const f32x4*)(p + 4);
  u16x8 r;
#pragma unroll
  for (int j = 0; j < 4; j++) { r[j] = f2bf(a[j]); r[4 + j] = f2bf(b[j]); }
  return r;
}

// =====================================================================
// Convert pass v2: flat balanced 1-D grid (r10).
// =====================================================================
__global__ __launch_bounds__(256) void cvt_all(
    const float* __restrict__ x, const float* __restrict__ wq, const float* __restrict__ wk,
    const float* __restrict__ wv, const float* __restrict__ wo,
    unsigned short* __restrict__ Xb, unsigned short* __restrict__ Wb) {
  const size_t XN = (size_t)NTOK * 1024;        // 4M
  const size_t TOT = XN + (size_t)4 * 1024 * 1024;  // 8M
  for (size_t i = ((size_t)blockIdx.x * 256 + threadIdx.x) * 8; i < TOT;
       i += (size_t)gridDim.x * 256 * 8) {
    if (i < XN) {
      *(u16x8*)(Xb + i) = cvt8(x + i);
    } else {
      const size_t j = i - XN;
      const int w = (int)(j >> 20);   // which 1M-elem weight
      const float* src = (w == 0) ? wq : (w == 1) ? wk : (w == 2) ? wv : wo;
      *(u16x8*)(Wb + j) = cvt8(src + (j & (((size_t)1 << 20) - 1)));
    }
  }
}

// =====================================================================
// Async global->LDS staging with XOR-chunk permutation (verified r3):
// 16B chunk (row, c8) -> slot row*8 + (c8 ^ (row&7)).
// =====================================================================
template <int ROWS, int NWAVE>
__device__ __forceinline__ void stage_glds(const unsigned short* __restrict__ gbase,
                                           int rstride,
                                           unsigned short* __restrict__ lds,
                                           int wid, int lane) {
  constexpr int ISS = ROWS * 8 / (NWAVE * 64);
#pragma unroll
  for (int t = 0; t < ISS; ++t) {
    const int slot = (wid * ISS + t) * 64 + lane;
    const int row = slot >> 3;
    const int c8 = (slot & 7) ^ (row & 7);
    const unsigned short* gp = gbase + (size_t)row * rstride + c8 * 8;
    unsigned short* lp = lds + (size_t)(wid * ISS + t) * 512;   // wave-uniform, 1 KiB/issue
    __builtin_amdgcn_global_load_lds((const gu32*)gp, (lu32*)lp, 16, 0, 0);
  }
}

__device__ __forceinline__ bf16x8 frag_ld(const unsigned short* __restrict__ lds, int row, int c8) {
  const int slot = row * 8 + (c8 ^ (row & 7));
  return *(const bf16x8*)(lds + slot * 8);
}

#define SBAR do { __builtin_amdgcn_sched_barrier(0); \
                  asm volatile("s_barrier" ::: "memory"); \
                  __builtin_amdgcn_sched_barrier(0); } while (0)

// =====================================================================
// Output projection (r14, ~neutral-positive): gemm_lds structure with
// BK=128 — 16 barriers. FROZEN.
// =====================================================================
__global__ __launch_bounds__(256) void gemm_op_bk128(
    const unsigned short* __restrict__ A,   // [4096][1024] bf16 (attn out)
    const unsigned short* __restrict__ B,   // [1024][1024] bf16 (Wo rows)
    float* __restrict__ C) {                // [4096][1024] fp32
  constexpr int K = 1024;
  constexpr int MI = 4, NI = 2;
  __shared__ __align__(16) unsigned short As[2][128 * 64];   // 16 KiB x2 (half-K regions)
  __shared__ __align__(16) unsigned short Bs[2][64 * 64];    // 8 KiB x2

  const int tid = threadIdx.x;
  const int wid = tid >> 6;
  const int lane = tid & 63;
  const int quad = lane >> 4;
  const int c16 = lane & 15;
  const int wrow = wid >> 1, wcol = wid & 1;

  const int m0 = blockIdx.x * 128;   // m fastest -> same-A blocks share an XCD
  const int n0 = blockIdx.y * 64;

  f32x4 acc[MI][NI];
#pragma unroll
  for (int i = 0; i < MI; i++)
#pragma unroll
    for (int j = 0; j < NI; j++) acc[i][j] = f32x4{0.f, 0.f, 0.f, 0.f};

  for (int kb = 0; kb < K; kb += 128) {
    __syncthreads();
    stage_glds<128, 4>(A + (size_t)m0 * K + kb, K, As[0], wid, lane);
    stage_glds<128, 4>(A + (size_t)m0 * K + kb + 64, K, As[1], wid, lane);
    stage_glds<64, 4>(B + (size_t)n0 * K + kb, K, Bs[0], wid, lane);
    stage_glds<64, 4>(B + (size_t)n0 * K + kb + 64, K, Bs[1], wid, lane);
    __syncthreads();
#pragma unroll
    for (int ks = 0; ks < 4; ++ks) {
      const unsigned short* Asr = As[ks >> 1];
      const unsigned short* Bsr = Bs[ks >> 1];
      const int c8 = (ks & 1) * 4 + quad;
      bf16x8 af[MI], bfr[NI];
#pragma unroll
      for (int i = 0; i < MI; i++)
        af[i] = frag_ld(Asr, wrow * 64 + i * 16 + c16, c8);
#pragma unroll
      for (int j = 0; j < NI; j++)
        bfr[j] = frag_ld(Bsr, wcol * 32 + j * 16 + c16, c8);
#pragma unroll
      for (int i = 0; i < MI; i++)
#pragma unroll
        for (int j = 0; j < NI; j++) acc[i][j] = MFMA16(af[i], bfr[j], acc[i][j]);
    }
  }

#pragma unroll
  for (int i = 0; i < MI; i++) {
#pragma unroll
    for (int j = 0; j < NI; j++) {
      const int row = m0 + wrow * 64 + i * 16 + quad * 4;
      const int col = n0 + wcol * 32 + j * 16 + c16;
#pragma unroll
      for (int r = 0; r < 4; r++)
        C[(size_t)(row + r) * 1024 + col] = acc[i][j][r];
    }
  }
}

// =====================================================================
// QKV projection r15: 256x192-tile GEMM, TWO phases per 2-tile pair
// (48 MFMA each) via a THIRD B buffer — the 3-buffer scheme removes
// the region conflict that blocked 2-phase merging (r11 note). Barrier
// amortization is the only 2/2-win lever class this session (r8 +1.2,
// r11 +3.7). 16 phases x 1 barrier = 16 (was 32). No VGPR growth: the
// lda8(mo0)/mm24(0)/lda8(mo4)/mm24(4) substructure is kept per phase.
// LDS 136 KB (As 2x32K + Bs 3x24K), 1 block/CU (unchanged).
//
// Per-wave issue ledger (7 glds/phase: A(t+1):4 + B(t+2):3):
//   phase t ends vmcnt(3): outstanding = carried B(t+1):3 + 7 = 10,
//   retires 7 (A(t+1)+B(t+1), read next phase), leaves B(t+2):3.
// Region audit: As[(t+1)&1] last read phase t-1; Bs[(t+2)%3] last read
//   phase t-1 — all readers retired >= 1 barrier before the stage.
// Phase 14 stages only A(15), ends vmcnt(0). Phase 15 stages nothing.
// =====================================================================
__global__ __launch_bounds__(512) void gemm_2ph_w192(
    const unsigned short* __restrict__ A,   // [4096][1024] bf16
    const unsigned short* __restrict__ B,   // [3072][1024] bf16 (Wq|Wk|Wv rows)
    unsigned short* __restrict__ C) {       // [4096][3072] bf16
  constexpr int K = 1024;
  __shared__ __align__(16) unsigned short As[2][256 * 64];   // 32 KiB x2
  __shared__ __align__(16) unsigned short Bs[3][192 * 64];   // 24 KiB x3

  const int tid = threadIdx.x;
  const int wid = tid >> 6, lane = tid & 63;
  const int quad = lane >> 4, c16 = lane & 15;
  const int wr = wid >> 2;        // 0..1  -> 128 output rows
  const int wc = wid & 3;         // 0..3  -> 48 output cols

  const int bid = blockIdx.x;
  const int swz = (bid & 7) * 32 + (bid >> 3);
  const int m0 = (swz >> 4) * 256;
  const int n0 = (swz & 15) * 192;

  const unsigned short* Abase = A + (size_t)m0 * K;
  const unsigned short* Bbase = B + (size_t)n0 * K;

  f32x4 acc[8][3];
#pragma unroll
  for (int i = 0; i < 8; i++)
#pragma unroll
    for (int j = 0; j < 3; j++) acc[i][j] = f32x4{0.f, 0.f, 0.f, 0.f};

  bf16x8 af[4][2];   // 4 m-rows x 2 ks (reloaded mid-phase for mo4)
  bf16x8 bf0[3];     // B frags ks=0
  bf16x8 bf1[3];     // B frags ks=1

  auto lda8 = [&](const unsigned short* asb, int mo) {
#pragma unroll
    for (int mi = 0; mi < 4; mi++)
#pragma unroll
      for (int ks = 0; ks < 2; ks++)
        af[mi][ks] = frag_ld(asb, wr * 128 + (mo + mi) * 16 + c16, ks * 4 + quad);
  };
  auto ldb6 = [&](const unsigned short* bsb) {
#pragma unroll
    for (int ni = 0; ni < 3; ni++) {
      bf0[ni] = frag_ld(bsb, wc * 48 + ni * 16 + c16, quad);
      bf1[ni] = frag_ld(bsb, wc * 48 + ni * 16 + c16, 4 + quad);
    }
  };
  auto mm24 = [&](int mo) {   // 24-MFMA half-phase
    __builtin_amdgcn_s_setprio(1);
#pragma unroll
    for (int mi = 0; mi < 4; mi++)
#pragma unroll
      for (int ni = 0; ni < 3; ni++) {
        acc[mo + mi][ni] = MFMA16(af[mi][0], bf0[ni], acc[mo + mi][ni]);
        acc[mo + mi][ni] = MFMA16(af[mi][1], bf1[ni], acc[mo + mi][ni]);
      }
    __builtin_amdgcn_s_setprio(0);
  };

  // ---- prologue: B(0)->Bs0 [3], A(0)->As0 [4], B(1)->Bs1 [3]
  stage_glds<192, 8>(Bbase, K, Bs[0], wid, lane);
  stage_glds<128, 8>(Abase, K, As[0], wid, lane);
  stage_glds<128, 8>(Abase + (size_t)128 * K, K, As[0] + 8192, wid, lane);
  stage_glds<192, 8>(Bbase + 64, K, Bs[1], wid, lane);
  asm volatile("s_waitcnt vmcnt(3)" ::: "memory");   // tile 0 landed; B(1) in flight
  SBAR;

  // ---- phases t = 0..13: stage A(t+1) + B(t+2); compute tile t
#pragma unroll 2
  for (int t = 0; t < 14; ++t) {
    const int abuf = t & 1;
    const unsigned short* AsR = As[abuf];
    unsigned short* AsW = As[abuf ^ 1];
    const unsigned short* BsR = Bs[t % 3];
    unsigned short* BsW = Bs[(t + 2) % 3];
    const int kb1 = (t + 1) * 64, kb2 = (t + 2) * 64;

    lda8(AsR, 0); ldb6(BsR);
    stage_glds<128, 8>(Abase + kb1, K, AsW, wid, lane);
    stage_glds<128, 8>(Abase + (size_t)128 * K + kb1, K, AsW + 8192, wid, lane);
    stage_glds<192, 8>(Bbase + kb2, K, BsW, wid, lane);
    mm24(0);
    lda8(AsR, 4);
    mm24(4);
    asm volatile("s_waitcnt vmcnt(3)" ::: "memory");   // A(t+1)+B(t+1) landed
    SBAR;
  }

  // ---- phase 14: stage only A(15); full drain
  {
    const int kb1 = 15 * 64;
    lda8(As[0], 0); ldb6(Bs[2]);   // 14 % 3 == 2
    stage_glds<128, 8>(Abase + kb1, K, As[1], wid, lane);
    stage_glds<128, 8>(Abase + (size_t)128 * K + kb1, K, As[1] + 8192, wid, lane);
    mm24(0);
    lda8(As[0], 4);
    mm24(4);
    asm volatile("s_waitcnt vmcnt(0)" ::: "memory");   // A(15)+B(15) landed
    SBAR;
  }
  // ---- phase 15: compute tile 15, nothing in flight
  {
    lda8(As[1], 0); ldb6(Bs[0]);   // 15 % 3 == 0 (B(15) staged phase 13)
    mm24(0);
    lda8(As[1], 4);
    mm24(4);
  }

#pragma unroll
  for (int mi = 0; mi < 8; mi++) {
#pragma unroll
    for (int ni = 0; ni < 3; ni++) {
      const int row = m0 + wr * 128 + mi * 16 + quad * 4;
      const int col = n0 + wc * 48 + ni * 16 + c16;
#pragma unroll
      for (int r = 0; r < 4; r++)
        C[(size_t)(row + r) * 3072 + col] = f2bf(acc[mi][ni][r]);
    }
  }
}

// =====================================================================
// Flash attention v14 (causal) — single-barrier pipeline, Vt dbuf
// (verified r7-r14: 41.2-43.2 µs). Structural floor. FROZEN.
// =====================================================================
__device__ __forceinline__ int vt_idx(int d, int kv) {
  int ck = kv >> 3;
  int s = ((d >> 3) ^ d) & 7;
  return d * 64 + ((ck ^ s) << 3) + (kv & 7);
}

struct AttnShared {
  unsigned short Kt[2][64 * 64];   // XOR-chunk swizzled K rows (8 KB x2)
  unsigned short Vt[2][64 * 64];   // vt_idx-swizzled V^T (8 KB x2)
  unsigned short Pt[4][16 * 64];   // per-wave 16x64 XOR-chunk P^T tile (8 KB)
};

__global__ __launch_bounds__(256) void attn_kernel(
    const unsigned short* __restrict__ QKV,   // [NTOK][3072]: Q | K | V (bf16)
    unsigned short* __restrict__ Oa) {        // [NTOK][1024] bf16
  __shared__ AttnShared sh;
  const int h = blockIdx.x;
  const int b = blockIdx.y;
  const int t = 31 - blockIdx.z;   // long tiles first (z is slowest dim)
  const int tid = threadIdx.x;
  const int wid = tid >> 6, lane = tid & 63;
  const int quad = lane >> 4, c16 = lane & 15;
  const size_t tokbase = (size_t)b * SEQ;
  const int q0 = t * 64;
  const int nkv = t + 1;

  // Q fragments (B-operand), scaled by 0.125 * log2(e)
  const unsigned short* qp = QKV + (tokbase + q0 + wid * 16 + c16) * 3072 + h * 64;
  bf16x8 qf[2];
#pragma unroll
  for (int ks = 0; ks < 2; ++ks) {
    u16x8 u = *(const u16x8*)(qp + ks * 32 + quad * 8);
    bf16x8 tq;
#pragma unroll
    for (int j = 0; j < 8; j++) tq[j] = (short)f2bf(0.1803368801f * bf2f(u[j]));
    qf[ks] = tq;
  }

  const unsigned short* kbase = QKV + tokbase * 3072 + 1024 + h * 64;
  const unsigned short* vbase = QKV + tokbase * 3072 + 2048 + h * 64;
  const int vkv = (tid >> 4) * 4;   // V stager: 4 kv rows
  const int vd = (tid & 15) * 4;    //           4 d cols

  f32x4 o[4];
  float lacc = 0.f;
#pragma unroll
  for (int nt = 0; nt < 4; nt++) o[nt] = f32x4{0.f, 0.f, 0.f, 0.f};
  unsigned short* PtW = sh.Pt[wid];
  const int pt_sub = (quad & 1) * 4;
  const int pt_c8h = quad >> 1;

  // ---- prologue: stage Kt[0]; load V(0) regs; write Vt[0] (pre-barrier)
  stage_glds<64, 4>(kbase, 3072, sh.Kt[0], wid, lane);
  u16x4 vr[4];
#pragma unroll
  for (int i = 0; i < 4; i++)
    vr[i] = *(const u16x4*)(vbase + (size_t)(vkv + i) * 3072 + vd);
#pragma unroll
  for (int dd = 0; dd < 4; ++dd) {   // compiler inserts vmcnt wait on vr here
    uint2 w;
    w.x = (unsigned int)vr[0][dd] | ((unsigned int)vr[1][dd] << 16);
    w.y = (unsigned int)vr[2][dd] | ((unsigned int)vr[3][dd] << 16);
    *(uint2*)&sh.Vt[0][vt_idx(vd + dd, vkv)] = w;
  }

  for (int kt = 0; kt < nkv; ++kt) {
    const int buf = kt & 1;
    // ONE barrier: publishes Vt[buf] writes (prev iter / prologue), drains
    // Kt[buf] glds (syncthreads waits vmcnt 0), frees Vt[buf^1]+Kt[buf^1].
    __syncthreads();

    const bool pf = (kt + 1 < nkv);
    if (pf) {   // issue next tile's K glds + V reg loads (fly over compute)
      const size_t nofs = (size_t)(kt + 1) * 64;
      stage_glds<64, 4>(kbase + nofs * 3072, 3072, sh.Kt[buf ^ 1], wid, lane);
#pragma unroll
      for (int i = 0; i < 4; i++)
        vr[i] = *(const u16x4*)(vbase + (nofs + vkv + i) * 3072 + vd);
    }

    // ---- S^T = K (Q*scale*log2e)^T - 16 : lane holds (kv=nt*16+quad*4+r, q=c16) ----
    const unsigned short* KtB = sh.Kt[buf];
    f32x4 st[4];
    __builtin_amdgcn_s_setprio(1);   // T5
#pragma unroll
    for (int nt = 0; nt < 4; ++nt) {
      f32x4 a = f32x4{-16.f, -16.f, -16.f, -16.f};
      a = MFMA16(frag_ld(KtB, nt * 16 + c16, quad), qf[0], a);
      a = MFMA16(frag_ld(KtB, nt * 16 + c16, 4 + quad), qf[1], a);
      st[nt] = a;
    }
    __builtin_amdgcn_s_setprio(0);
    if (kt == nkv - 1) {   // diagonal kv-tile
      const int kv0 = kt * 64;
      const int qg = q0 + wid * 16 + c16;
#pragma unroll
      for (int nt = 0; nt < 4; nt++)
#pragma unroll
        for (int r = 0; r < 4; r++) {
          int kg = kv0 + nt * 16 + quad * 4 + r;
          if (kg > qg) st[nt][r] = -1e30f;
        }
    }

    // ---- p = exp2(s); v_perm trunc-pack; XOR-chunk Pt writes ----
#pragma unroll
    for (int nt = 0; nt < 4; nt++) {
      float p0 = __builtin_amdgcn_exp2f(st[nt][0]);
      float p1 = __builtin_amdgcn_exp2f(st[nt][1]);
      float p2 = __builtin_amdgcn_exp2f(st[nt][2]);
      float p3 = __builtin_amdgcn_exp2f(st[nt][3]);
      lacc += (p0 + p1) + (p2 + p3);
      uint2 w;
      w.x = pkbf_trunc(p1, p0);
      w.y = pkbf_trunc(p3, p2);
      const int c8w = 2 * nt + pt_c8h;
      const int slot = c16 * 8 + (c8w ^ (c16 & 7));
      *(uint2*)&PtW[slot * 8 + pt_sub] = w;
    }

    if (pf) {   // write NEXT tile's V into the other Vt buffer (no barrier
                // needed before PV: PV reads Vt[buf], writes go to Vt[buf^1])
#pragma unroll
      for (int dd = 0; dd < 4; ++dd) {   // compiler vmcnt-waits on vr
        uint2 w;
        w.x = (unsigned int)vr[0][dd] | ((unsigned int)vr[1][dd] << 16);
        w.y = (unsigned int)vr[2][dd] | ((unsigned int)vr[3][dd] << 16);
        *(uint2*)&sh.Vt[buf ^ 1][vt_idx(vd + dd, vkv)] = w;
      }
    }

    // ---- O^T += V^T P^T (wave-private Pt; lgkmcnt-ordered, no barrier) ----
    const unsigned short* VtB = sh.Vt[buf];
    __builtin_amdgcn_s_setprio(1);   // T5
#pragma unroll
    for (int ks = 0; ks < 2; ++ks) {
      bf16x8 pfrag = frag_ld(PtW, c16, ks * 4 + quad);
#pragma unroll
      for (int nt2 = 0; nt2 < 4; ++nt2) {
        bf16x8 vf = *(const bf16x8*)&VtB[vt_idx(nt2 * 16 + c16, ks * 32 + quad * 8)];
        o[nt2] = MFMA16(vf, pfrag, o[nt2]);
      }
    }
    __builtin_amdgcn_s_setprio(0);
  }

  // ---- epilogue: l across quads (2 shuffles); packed dwordx2 stores ----
  lacc += __shfl_xor(lacc, 16);
  lacc += __shfl_xor(lacc, 32);
  const float linv = 1.f / lacc;
  const size_t row = tokbase + q0 + wid * 16 + c16;
#pragma unroll
  for (int nt2 = 0; nt2 < 4; nt2++) {
    uint2 w;
    w.x = (unsigned int)f2bf(o[nt2][0] * linv) | ((unsigned int)f2bf(o[nt2][1] * linv) << 16);
    w.y = (unsigned int)f2bf(o[nt2][2] * linv) | ((unsigned int)f2bf(o[nt2][3] * linv) << 16);
    *(uint2*)&Oa[row * 1024 + h * 64 + nt2 * 16 + quad * 4] = w;
  }
}

// =====================================================================
// Round-2 fallback GEMM (fp32 staging) — used only if ws_size < 40 MB.
// =====================================================================
template <int BM, int BN, int LDC, bool AF32, bool CF32>
__global__ __launch_bounds__(256) void gemm_bt(
    const void* __restrict__ Av, const float* __restrict__ W0, const float* __restrict__ W1,
    const float* __restrict__ W2, void* __restrict__ Cv) {
  constexpr int K = 1024;
  constexpr int LDS_LD = 72;
  constexpr int MI = BM / 32, NI = BN / 32;
  __shared__ __align__(16) unsigned short As[BM][LDS_LD];
  __shared__ __align__(16) unsigned short Bs[BN][LDS_LD];
  const int tid = threadIdx.x, wid = tid >> 6, lane = tid & 63;
  const int quad = lane >> 4, c16 = lane & 15;
  const int wrow = wid >> 1, wcol = wid & 1;
  const float* W = (blockIdx.z == 0) ? W0 : (blockIdx.z == 1 ? W1 : W2);
  const int m0 = blockIdx.y * BM, n0 = blockIdx.x * BN, cofs = blockIdx.z * 1024;
  f32x4 acc[MI][NI];
#pragma unroll
  for (int i = 0; i < MI; i++)
#pragma unroll
    for (int j = 0; j < NI; j++) acc[i][j] = f32x4{0.f, 0.f, 0.f, 0.f};
  for (int kb = 0; kb < K; kb += 64) {
    __syncthreads();
#pragma unroll
    for (int c = tid; c < BM * 8; c += 256) {
      int row = c >> 3, c8 = c & 7;
      if constexpr (AF32)
        *(u16x8*)&As[row][c8 * 8] = cvt8((const float*)Av + (size_t)(m0 + row) * K + kb + c8 * 8);
      else
        *(u16x8*)&As[row][c8 * 8] = *(const u16x8*)((const unsigned short*)Av + (size_t)(m0 + row) * K + kb + c8 * 8);
    }
#pragma unroll
    for (int c = tid; c < BN * 8; c += 256) {
      int row = c >> 3, c8 = c & 7;
      *(u16x8*)&Bs[row][c8 * 8] = cvt8(W + (size_t)(n0 + row) * K + kb + c8 * 8);
    }
    __syncthreads();
#pragma unroll
    for (int ks = 0; ks < 2; ++ks) {
      bf16x8 af[MI], bfr[NI];
#pragma unroll
      for (int i = 0; i < MI; i++)
        af[i] = *(const bf16x8*)&As[wrow * (BM / 2) + i * 16 + c16][ks * 32 + quad * 8];
#pragma unroll
      for (int j = 0; j < NI; j++)
        bfr[j] = *(const bf16x8*)&Bs[wcol * (BN / 2) + j * 16 + c16][ks * 32 + quad * 8];
#pragma unroll
      for (int i = 0; i < MI; i++)
#pragma unroll
        for (int j = 0; j < NI; j++) acc[i][j] = MFMA16(af[i], bfr[j], acc[i][j]);
    }
  }
#pragma unroll
  for (int i = 0; i < MI; i++)
#pragma unroll
    for (int j = 0; j < NI; j++) {
      int row = m0 + wrow * (BM / 2) + i * 16 + quad * 4;
      int col = n0 + wcol * (BN / 2) + j * 16 + c16 + cofs;
#pragma unroll
      for (int r = 0; r < 4; r++) {
        if constexpr (CF32) ((float*)Cv)[(size_t)(row + r) * LDC + col] = acc[i][j][r];
        else ((unsigned short*)Cv)[(size_t)(row + r) * LDC + col] = f2bf(acc[i][j][r]);
      }
    }
}

// =====================================================================
extern "C" void kernel_launch(void* const* d_in, const int* in_sizes, int n_in,
                              void* d_out, int out_size, void* d_ws, size_t ws_size,
                              hipStream_t stream) {
  const float* x = (const float*)d_in[0];
  const float* Wq = (const float*)d_in[2];
  const float* Wk = (const float*)d_in[3];
  const float* Wv = (const float*)d_in[4];
  const float* Wo = (const float*)d_in[5];
  float* out = (float*)d_out;

  unsigned short* QKV = (unsigned short*)d_ws;                 // [4096][3072] bf16 (24MB)
  unsigned short* Wb = QKV + (size_t)NTOK * 3072;              // 4 x [1024][1024] bf16 (8MB)
  unsigned short* Xb = Wb + (size_t)4 * 1024 * 1024;           // [4096][1024] bf16 (8MB), == AT
  unsigned short* AT = Xb;

  if (ws_size >= (size_t)40 * 1024 * 1024) {
    // convert: flat balanced grid (2048 blocks, 2 iters/thread exactly)
    cvt_all<<<dim3(2048), 256, 0, stream>>>(x, Wq, Wk, Wv, Wo, Xb, Wb);
    // fused QKV projection: 256x192, TWO phases via 3-buffer B (r15)
    gemm_2ph_w192<<<dim3(256), 512, 0, stream>>>(Xb, Wb, QKV);
    // flash attention v14: single-barrier pipeline, Vt double-buffer
    attn_kernel<<<dim3(NH, 2, 32), 256, 0, stream>>>(QKV, AT);
    // output projection: gemm_lds structure with BK=128 (r14)
    gemm_op_bk128<<<dim3(32, 16), 256, 0, stream>>>(
        AT, Wb + (size_t)3 * 1024 * 1024, out);
  } else {
    unsigned short* QKV2 = (unsigned short*)d_ws;
    unsigned short* AT2 = QKV2 + (size_t)NTOK * 3072;
    gemm_bt<128, 128, 3072, true, false><<<dim3(8, 32, 3), 256, 0, stream>>>(x, Wq, Wk, Wv, QKV2);
    attn_kernel<<<dim3(NH, 2, 32), 256, 0, stream>>>(QKV2, AT2);
    gemm_bt<64, 64, 1024, false, true><<<dim3(16, 64, 1), 256, 0, stream>>>(AT2, Wo, Wo, Wo, out);
  }
}

// Round 16
// 168.251 us; speedup vs baseline: 1.0410x; 1.0014x over previous
//
#include <hip/hip_runtime.h>
#include <hip/hip_bf16.h>

// ---- types ----
typedef short bf16x8 __attribute__((ext_vector_type(8)));          // 8 bf16 = 4 VGPRs (MFMA A/B frag)
typedef unsigned short u16x8 __attribute__((ext_vector_type(8)));
typedef unsigned short u16x4 __attribute__((ext_vector_type(4)));
typedef float f32x4 __attribute__((ext_vector_type(4)));           // MFMA C/D frag

typedef unsigned int __attribute__((address_space(1))) gu32;       // global
typedef unsigned int __attribute__((address_space(3))) lu32;       // LDS

#define MFMA16(a, b, c) __builtin_amdgcn_mfma_f32_16x16x32_bf16((a), (b), (c), 0, 0, 0)

constexpr int SEQ = 2048;
constexpr int NH = 16;
constexpr int NTOK = 2 * SEQ;  // 4096

__device__ __forceinline__ float bf2f(unsigned short u) {
  union { unsigned int i; float f; } v; v.i = ((unsigned int)u) << 16; return v.f;
}
__device__ __forceinline__ unsigned short f2bf(float f) {
  __hip_bfloat16 h = __float2bfloat16(f);   // RNE
  return __builtin_bit_cast(unsigned short, h);
}
// pack two fp32 -> bf16 pair by TRUNCATION via one v_perm_b32 (hi<<16 | lo)
__device__ __forceinline__ unsigned int pkbf_trunc(float hi, float lo) {
  return __builtin_amdgcn_perm(__builtin_bit_cast(unsigned int, hi),
                               __builtin_bit_cast(unsigned int, lo), 0x07060302u);
}
__device__ __forceinline__ u16x8 cvt8(const float* __restrict__ p) {
  f32x4 a = *(const f32x4*)p;
  f32x4 b = *(const f32x4*)(p + 4);
  u16x8 r;
#pragma unroll
  for (int j = 0; j < 4; j++) { r[j] = f2bf(a[j]); r[4 + j] = f2bf(b[j]); }
  return r;
}

// =====================================================================
// Convert pass v3 (r16): 4096 blocks -> exactly ONE vec8 per thread
// (8M elems = 4096 x 256 x 8); no grid-stride loop, one uniform branch.
// =====================================================================
__global__ __launch_bounds__(256) void cvt_all(
    const float* __restrict__ x, const float* __restrict__ wq, const float* __restrict__ wk,
    const float* __restrict__ wv, const float* __restrict__ wo,
    unsigned short* __restrict__ Xb, unsigned short* __restrict__ Wb) {
  const size_t XN = (size_t)NTOK * 1024;        // 4M
  const size_t i = ((size_t)blockIdx.x * 256 + threadIdx.x) * 8;
  if (i < XN) {
    *(u16x8*)(Xb + i) = cvt8(x + i);
  } else {
    const size_t j = i - XN;
    const int w = (int)(j >> 20);   // which 1M-elem weight
    const float* src = (w == 0) ? wq : (w == 1) ? wk : (w == 2) ? wv : wo;
    *(u16x8*)(Wb + j) = cvt8(src + (j & (((size_t)1 << 20) - 1)));
  }
}

// =====================================================================
// Async global->LDS staging with XOR-chunk permutation (verified r3):
// 16B chunk (row, c8) -> slot row*8 + (c8 ^ (row&7)).
// =====================================================================
template <int ROWS, int NWAVE>
__device__ __forceinline__ void stage_glds(const unsigned short* __restrict__ gbase,
                                           int rstride,
                                           unsigned short* __restrict__ lds,
                                           int wid, int lane) {
  constexpr int ISS = ROWS * 8 / (NWAVE * 64);
#pragma unroll
  for (int t = 0; t < ISS; ++t) {
    const int slot = (wid * ISS + t) * 64 + lane;
    const int row = slot >> 3;
    const int c8 = (slot & 7) ^ (row & 7);
    const unsigned short* gp = gbase + (size_t)row * rstride + c8 * 8;
    unsigned short* lp = lds + (size_t)(wid * ISS + t) * 512;   // wave-uniform, 1 KiB/issue
    __builtin_amdgcn_global_load_lds((const gu32*)gp, (lu32*)lp, 16, 0, 0);
  }
}

__device__ __forceinline__ bf16x8 frag_ld(const unsigned short* __restrict__ lds, int row, int c8) {
  const int slot = row * 8 + (c8 ^ (row & 7));
  return *(const bf16x8*)(lds + slot * 8);
}

#define SBAR do { __builtin_amdgcn_sched_barrier(0); \
                  asm volatile("s_barrier" ::: "memory"); \
                  __builtin_amdgcn_sched_barrier(0); } while (0)

// =====================================================================
// Output projection (r14): gemm_lds structure with BK=128 — 16
// barriers. FROZEN (r9/r12 sync rewrites regressed; BK=256 would drop
// to 1 block/CU and lose co-resident hiding).
// =====================================================================
__global__ __launch_bounds__(256) void gemm_op_bk128(
    const unsigned short* __restrict__ A,   // [4096][1024] bf16 (attn out)
    const unsigned short* __restrict__ B,   // [1024][1024] bf16 (Wo rows)
    float* __restrict__ C) {                // [4096][1024] fp32
  constexpr int K = 1024;
  constexpr int MI = 4, NI = 2;
  __shared__ __align__(16) unsigned short As[2][128 * 64];   // 16 KiB x2 (half-K regions)
  __shared__ __align__(16) unsigned short Bs[2][64 * 64];    // 8 KiB x2

  const int tid = threadIdx.x;
  const int wid = tid >> 6;
  const int lane = tid & 63;
  const int quad = lane >> 4;
  const int c16 = lane & 15;
  const int wrow = wid >> 1, wcol = wid & 1;

  const int m0 = blockIdx.x * 128;   // m fastest -> same-A blocks share an XCD
  const int n0 = blockIdx.y * 64;

  f32x4 acc[MI][NI];
#pragma unroll
  for (int i = 0; i < MI; i++)
#pragma unroll
    for (int j = 0; j < NI; j++) acc[i][j] = f32x4{0.f, 0.f, 0.f, 0.f};

  for (int kb = 0; kb < K; kb += 128) {
    __syncthreads();
    stage_glds<128, 4>(A + (size_t)m0 * K + kb, K, As[0], wid, lane);
    stage_glds<128, 4>(A + (size_t)m0 * K + kb + 64, K, As[1], wid, lane);
    stage_glds<64, 4>(B + (size_t)n0 * K + kb, K, Bs[0], wid, lane);
    stage_glds<64, 4>(B + (size_t)n0 * K + kb + 64, K, Bs[1], wid, lane);
    __syncthreads();
#pragma unroll
    for (int ks = 0; ks < 4; ++ks) {
      const unsigned short* Asr = As[ks >> 1];
      const unsigned short* Bsr = Bs[ks >> 1];
      const int c8 = (ks & 1) * 4 + quad;
      bf16x8 af[MI], bfr[NI];
#pragma unroll
      for (int i = 0; i < MI; i++)
        af[i] = frag_ld(Asr, wrow * 64 + i * 16 + c16, c8);
#pragma unroll
      for (int j = 0; j < NI; j++)
        bfr[j] = frag_ld(Bsr, wcol * 32 + j * 16 + c16, c8);
#pragma unroll
      for (int i = 0; i < MI; i++)
#pragma unroll
        for (int j = 0; j < NI; j++) acc[i][j] = MFMA16(af[i], bfr[j], acc[i][j]);
    }
  }

#pragma unroll
  for (int i = 0; i < MI; i++) {
#pragma unroll
    for (int j = 0; j < NI; j++) {
      const int row = m0 + wrow * 64 + i * 16 + quad * 4;
      const int col = n0 + wcol * 32 + j * 16 + c16;
#pragma unroll
      for (int r = 0; r < 4; r++)
        C[(size_t)(row + r) * 1024 + col] = acc[i][j][r];
    }
  }
}

// =====================================================================
// QKV projection (r15, verified best): 256x192-tile GEMM, TWO phases
// per 2-tile pair via 3-buffer B. 16 barriers. vmcnt(3) per phase.
// At its 2-buffer-A structural limit (As 3x would exceed 160 KB).
// FROZEN.
// =====================================================================
__global__ __launch_bounds__(512) void gemm_2ph_w192(
    const unsigned short* __restrict__ A,   // [4096][1024] bf16
    const unsigned short* __restrict__ B,   // [3072][1024] bf16 (Wq|Wk|Wv rows)
    unsigned short* __restrict__ C) {       // [4096][3072] bf16
  constexpr int K = 1024;
  __shared__ __align__(16) unsigned short As[2][256 * 64];   // 32 KiB x2
  __shared__ __align__(16) unsigned short Bs[3][192 * 64];   // 24 KiB x3

  const int tid = threadIdx.x;
  const int wid = tid >> 6, lane = tid & 63;
  const int quad = lane >> 4, c16 = lane & 15;
  const int wr = wid >> 2;        // 0..1  -> 128 output rows
  const int wc = wid & 3;         // 0..3  -> 48 output cols

  const int bid = blockIdx.x;
  const int swz = (bid & 7) * 32 + (bid >> 3);
  const int m0 = (swz >> 4) * 256;
  const int n0 = (swz & 15) * 192;

  const unsigned short* Abase = A + (size_t)m0 * K;
  const unsigned short* Bbase = B + (size_t)n0 * K;

  f32x4 acc[8][3];
#pragma unroll
  for (int i = 0; i < 8; i++)
#pragma unroll
    for (int j = 0; j < 3; j++) acc[i][j] = f32x4{0.f, 0.f, 0.f, 0.f};

  bf16x8 af[4][2];   // 4 m-rows x 2 ks (reloaded mid-phase for mo4)
  bf16x8 bf0[3];     // B frags ks=0
  bf16x8 bf1[3];     // B frags ks=1

  auto lda8 = [&](const unsigned short* asb, int mo) {
#pragma unroll
    for (int mi = 0; mi < 4; mi++)
#pragma unroll
      for (int ks = 0; ks < 2; ks++)
        af[mi][ks] = frag_ld(asb, wr * 128 + (mo + mi) * 16 + c16, ks * 4 + quad);
  };
  auto ldb6 = [&](const unsigned short* bsb) {
#pragma unroll
    for (int ni = 0; ni < 3; ni++) {
      bf0[ni] = frag_ld(bsb, wc * 48 + ni * 16 + c16, quad);
      bf1[ni] = frag_ld(bsb, wc * 48 + ni * 16 + c16, 4 + quad);
    }
  };
  auto mm24 = [&](int mo) {   // 24-MFMA half-phase
    __builtin_amdgcn_s_setprio(1);
#pragma unroll
    for (int mi = 0; mi < 4; mi++)
#pragma unroll
      for (int ni = 0; ni < 3; ni++) {
        acc[mo + mi][ni] = MFMA16(af[mi][0], bf0[ni], acc[mo + mi][ni]);
        acc[mo + mi][ni] = MFMA16(af[mi][1], bf1[ni], acc[mo + mi][ni]);
      }
    __builtin_amdgcn_s_setprio(0);
  };

  // ---- prologue: B(0)->Bs0 [3], A(0)->As0 [4], B(1)->Bs1 [3]
  stage_glds<192, 8>(Bbase, K, Bs[0], wid, lane);
  stage_glds<128, 8>(Abase, K, As[0], wid, lane);
  stage_glds<128, 8>(Abase + (size_t)128 * K, K, As[0] + 8192, wid, lane);
  stage_glds<192, 8>(Bbase + 64, K, Bs[1], wid, lane);
  asm volatile("s_waitcnt vmcnt(3)" ::: "memory");   // tile 0 landed; B(1) in flight
  SBAR;

  // ---- phases t = 0..13: stage A(t+1) + B(t+2); compute tile t
#pragma unroll 2
  for (int t = 0; t < 14; ++t) {
    const int abuf = t & 1;
    const unsigned short* AsR = As[abuf];
    unsigned short* AsW = As[abuf ^ 1];
    const unsigned short* BsR = Bs[t % 3];
    unsigned short* BsW = Bs[(t + 2) % 3];
    const int kb1 = (t + 1) * 64, kb2 = (t + 2) * 64;

    lda8(AsR, 0); ldb6(BsR);
    stage_glds<128, 8>(Abase + kb1, K, AsW, wid, lane);
    stage_glds<128, 8>(Abase + (size_t)128 * K + kb1, K, AsW + 8192, wid, lane);
    stage_glds<192, 8>(Bbase + kb2, K, BsW, wid, lane);
    mm24(0);
    lda8(AsR, 4);
    mm24(4);
    asm volatile("s_waitcnt vmcnt(3)" ::: "memory");   // A(t+1)+B(t+1) landed
    SBAR;
  }

  // ---- phase 14: stage only A(15); full drain
  {
    const int kb1 = 15 * 64;
    lda8(As[0], 0); ldb6(Bs[2]);   // 14 % 3 == 2
    stage_glds<128, 8>(Abase + kb1, K, As[1], wid, lane);
    stage_glds<128, 8>(Abase + (size_t)128 * K + kb1, K, As[1] + 8192, wid, lane);
    mm24(0);
    lda8(As[0], 4);
    mm24(4);
    asm volatile("s_waitcnt vmcnt(0)" ::: "memory");   // A(15)+B(15) landed
    SBAR;
  }
  // ---- phase 15: compute tile 15, nothing in flight
  {
    lda8(As[1], 0); ldb6(Bs[0]);   // 15 % 3 == 0 (B(15) staged phase 13)
    mm24(0);
    lda8(As[1], 4);
    mm24(4);
  }

#pragma unroll
  for (int mi = 0; mi < 8; mi++) {
#pragma unroll
    for (int ni = 0; ni < 3; ni++) {
      const int row = m0 + wr * 128 + mi * 16 + quad * 4;
      const int col = n0 + wc * 48 + ni * 16 + c16;
#pragma unroll
      for (int r = 0; r < 4; r++)
        C[(size_t)(row + r) * 3072 + col] = f2bf(acc[mi][ni][r]);
    }
  }
}

// =====================================================================
// Flash attention v14 (causal) — single-barrier pipeline, Vt dbuf
// (verified r7-r15: 41.2-43.2 µs). Structural floor for this
// decomposition: all 4 waves read the full Kt/Vt tiles (lane-only
// addressing) -> 4x LDS read duplication ~= 25 µs/CU of ds_read issue;
// fixing it needs the 8-warp 32x32 rewrite. FROZEN.
// =====================================================================
__device__ __forceinline__ int vt_idx(int d, int kv) {
  int ck = kv >> 3;
  int s = ((d >> 3) ^ d) & 7;
  return d * 64 + ((ck ^ s) << 3) + (kv & 7);
}

struct AttnShared {
  unsigned short Kt[2][64 * 64];   // XOR-chunk swizzled K rows (8 KB x2)
  unsigned short Vt[2][64 * 64];   // vt_idx-swizzled V^T (8 KB x2)
  unsigned short Pt[4][16 * 64];   // per-wave 16x64 XOR-chunk P^T tile (8 KB)
};

__global__ __launch_bounds__(256) void attn_kernel(
    const unsigned short* __restrict__ QKV,   // [NTOK][3072]: Q | K | V (bf16)
    unsigned short* __restrict__ Oa) {        // [NTOK][1024] bf16
  __shared__ AttnShared sh;
  const int h = blockIdx.x;
  const int b = blockIdx.y;
  const int t = 31 - blockIdx.z;   // long tiles first (z is slowest dim)
  const int tid = threadIdx.x;
  const int wid = tid >> 6, lane = tid & 63;
  const int quad = lane >> 4, c16 = lane & 15;
  const size_t tokbase = (size_t)b * SEQ;
  const int q0 = t * 64;
  const int nkv = t + 1;

  // Q fragments (B-operand), scaled by 0.125 * log2(e)
  const unsigned short* qp = QKV + (tokbase + q0 + wid * 16 + c16) * 3072 + h * 64;
  bf16x8 qf[2];
#pragma unroll
  for (int ks = 0; ks < 2; ++ks) {
    u16x8 u = *(const u16x8*)(qp + ks * 32 + quad * 8);
    bf16x8 tq;
#pragma unroll
    for (int j = 0; j < 8; j++) tq[j] = (short)f2bf(0.1803368801f * bf2f(u[j]));
    qf[ks] = tq;
  }

  const unsigned short* kbase = QKV + tokbase * 3072 + 1024 + h * 64;
  const unsigned short* vbase = QKV + tokbase * 3072 + 2048 + h * 64;
  const int vkv = (tid >> 4) * 4;   // V stager: 4 kv rows
  const int vd = (tid & 15) * 4;    //           4 d cols

  f32x4 o[4];
  float lacc = 0.f;
#pragma unroll
  for (int nt = 0; nt < 4; nt++) o[nt] = f32x4{0.f, 0.f, 0.f, 0.f};
  unsigned short* PtW = sh.Pt[wid];
  const int pt_sub = (quad & 1) * 4;
  const int pt_c8h = quad >> 1;

  // ---- prologue: stage Kt[0]; load V(0) regs; write Vt[0] (pre-barrier)
  stage_glds<64, 4>(kbase, 3072, sh.Kt[0], wid, lane);
  u16x4 vr[4];
#pragma unroll
  for (int i = 0; i < 4; i++)
    vr[i] = *(const u16x4*)(vbase + (size_t)(vkv + i) * 3072 + vd);
#pragma unroll
  for (int dd = 0; dd < 4; ++dd) {   // compiler inserts vmcnt wait on vr here
    uint2 w;
    w.x = (unsigned int)vr[0][dd] | ((unsigned int)vr[1][dd] << 16);
    w.y = (unsigned int)vr[2][dd] | ((unsigned int)vr[3][dd] << 16);
    *(uint2*)&sh.Vt[0][vt_idx(vd + dd, vkv)] = w;
  }

  for (int kt = 0; kt < nkv; ++kt) {
    const int buf = kt & 1;
    // ONE barrier: publishes Vt[buf] writes (prev iter / prologue), drains
    // Kt[buf] glds (syncthreads waits vmcnt 0), frees Vt[buf^1]+Kt[buf^1].
    __syncthreads();

    const bool pf = (kt + 1 < nkv);
    if (pf) {   // issue next tile's K glds + V reg loads (fly over compute)
      const size_t nofs = (size_t)(kt + 1) * 64;
      stage_glds<64, 4>(kbase + nofs * 3072, 3072, sh.Kt[buf ^ 1], wid, lane);
#pragma unroll
      for (int i = 0; i < 4; i++)
        vr[i] = *(const u16x4*)(vbase + (nofs + vkv + i) * 3072 + vd);
    }

    // ---- S^T = K (Q*scale*log2e)^T - 16 : lane holds (kv=nt*16+quad*4+r, q=c16) ----
    const unsigned short* KtB = sh.Kt[buf];
    f32x4 st[4];
    __builtin_amdgcn_s_setprio(1);   // T5
#pragma unroll
    for (int nt = 0; nt < 4; ++nt) {
      f32x4 a = f32x4{-16.f, -16.f, -16.f, -16.f};
      a = MFMA16(frag_ld(KtB, nt * 16 + c16, quad), qf[0], a);
      a = MFMA16(frag_ld(KtB, nt * 16 + c16, 4 + quad), qf[1], a);
      st[nt] = a;
    }
    __builtin_amdgcn_s_setprio(0);
    if (kt == nkv - 1) {   // diagonal kv-tile
      const int kv0 = kt * 64;
      const int qg = q0 + wid * 16 + c16;
#pragma unroll
      for (int nt = 0; nt < 4; nt++)
#pragma unroll
        for (int r = 0; r < 4; r++) {
          int kg = kv0 + nt * 16 + quad * 4 + r;
          if (kg > qg) st[nt][r] = -1e30f;
        }
    }

    // ---- p = exp2(s); v_perm trunc-pack; XOR-chunk Pt writes ----
#pragma unroll
    for (int nt = 0; nt < 4; nt++) {
      float p0 = __builtin_amdgcn_exp2f(st[nt][0]);
      float p1 = __builtin_amdgcn_exp2f(st[nt][1]);
      float p2 = __builtin_amdgcn_exp2f(st[nt][2]);
      float p3 = __builtin_amdgcn_exp2f(st[nt][3]);
      lacc += (p0 + p1) + (p2 + p3);
      uint2 w;
      w.x = pkbf_trunc(p1, p0);
      w.y = pkbf_trunc(p3, p2);
      const int c8w = 2 * nt + pt_c8h;
      const int slot = c16 * 8 + (c8w ^ (c16 & 7));
      *(uint2*)&PtW[slot * 8 + pt_sub] = w;
    }

    if (pf) {   // write NEXT tile's V into the other Vt buffer (no barrier
                // needed before PV: PV reads Vt[buf], writes go to Vt[buf^1])
#pragma unroll
      for (int dd = 0; dd < 4; ++dd) {   // compiler vmcnt-waits on vr
        uint2 w;
        w.x = (unsigned int)vr[0][dd] | ((unsigned int)vr[1][dd] << 16);
        w.y = (unsigned int)vr[2][dd] | ((unsigned int)vr[3][dd] << 16);
        *(uint2*)&sh.Vt[buf ^ 1][vt_idx(vd + dd, vkv)] = w;
      }
    }

    // ---- O^T += V^T P^T (wave-private Pt; lgkmcnt-ordered, no barrier) ----
    const unsigned short* VtB = sh.Vt[buf];
    __builtin_amdgcn_s_setprio(1);   // T5
#pragma unroll
    for (int ks = 0; ks < 2; ++ks) {
      bf16x8 pfrag = frag_ld(PtW, c16, ks * 4 + quad);
#pragma unroll
      for (int nt2 = 0; nt2 < 4; ++nt2) {
        bf16x8 vf = *(const bf16x8*)&VtB[vt_idx(nt2 * 16 + c16, ks * 32 + quad * 8)];
        o[nt2] = MFMA16(vf, pfrag, o[nt2]);
      }
    }
    __builtin_amdgcn_s_setprio(0);
  }

  // ---- epilogue: l across quads (2 shuffles); packed dwordx2 stores ----
  lacc += __shfl_xor(lacc, 16);
  lacc += __shfl_xor(lacc, 32);
  const float linv = 1.f / lacc;
  const size_t row = tokbase + q0 + wid * 16 + c16;
#pragma unroll
  for (int nt2 = 0; nt2 < 4; nt2++) {
    uint2 w;
    w.x = (unsigned int)f2bf(o[nt2][0] * linv) | ((unsigned int)f2bf(o[nt2][1] * linv) << 16);
    w.y = (unsigned int)f2bf(o[nt2][2] * linv) | ((unsigned int)f2bf(o[nt2][3] * linv) << 16);
    *(uint2*)&Oa[row * 1024 + h * 64 + nt2 * 16 + quad * 4] = w;
  }
}

// =====================================================================
// Round-2 fallback GEMM (fp32 staging) — used only if ws_size < 40 MB.
// =====================================================================
template <int BM, int BN, int LDC, bool AF32, bool CF32>
__global__ __launch_bounds__(256) void gemm_bt(
    const void* __restrict__ Av, const float* __restrict__ W0, const float* __restrict__ W1,
    const float* __restrict__ W2, void* __restrict__ Cv) {
  constexpr int K = 1024;
  constexpr int LDS_LD = 72;
  constexpr int MI = BM / 32, NI = BN / 32;
  __shared__ __align__(16) unsigned short As[BM][LDS_LD];
  __shared__ __align__(16) unsigned short Bs[BN][LDS_LD];
  const int tid = threadIdx.x, wid = tid >> 6, lane = tid & 63;
  const int quad = lane >> 4, c16 = lane & 15;
  const int wrow = wid >> 1, wcol = wid & 1;
  const float* W = (blockIdx.z == 0) ? W0 : (blockIdx.z == 1 ? W1 : W2);
  const int m0 = blockIdx.y * BM, n0 = blockIdx.x * BN, cofs = blockIdx.z * 1024;
  f32x4 acc[MI][NI];
#pragma unroll
  for (int i = 0; i < MI; i++)
#pragma unroll
    for (int j = 0; j < NI; j++) acc[i][j] = f32x4{0.f, 0.f, 0.f, 0.f};
  for (int kb = 0; kb < K; kb += 64) {
    __syncthreads();
#pragma unroll
    for (int c = tid; c < BM * 8; c += 256) {
      int row = c >> 3, c8 = c & 7;
      if constexpr (AF32)
        *(u16x8*)&As[row][c8 * 8] = cvt8((const float*)Av + (size_t)(m0 + row) * K + kb + c8 * 8);
      else
        *(u16x8*)&As[row][c8 * 8] = *(const u16x8*)((const unsigned short*)Av + (size_t)(m0 + row) * K + kb + c8 * 8);
    }
#pragma unroll
    for (int c = tid; c < BN * 8; c += 256) {
      int row = c >> 3, c8 = c & 7;
      *(u16x8*)&Bs[row][c8 * 8] = cvt8(W + (size_t)(n0 + row) * K + kb + c8 * 8);
    }
    __syncthreads();
#pragma unroll
    for (int ks = 0; ks < 2; ++ks) {
      bf16x8 af[MI], bfr[NI];
#pragma unroll
      for (int i = 0; i < MI; i++)
        af[i] = *(const bf16x8*)&As[wrow * (BM / 2) + i * 16 + c16][ks * 32 + quad * 8];
#pragma unroll
      for (int j = 0; j < NI; j++)
        bfr[j] = *(const bf16x8*)&Bs[wcol * (BN / 2) + j * 16 + c16][ks * 32 + quad * 8];
#pragma unroll
      for (int i = 0; i < MI; i++)
#pragma unroll
        for (int j = 0; j < NI; j++) acc[i][j] = MFMA16(af[i], bfr[j], acc[i][j]);
    }
  }
#pragma unroll
  for (int i = 0; i < MI; i++)
#pragma unroll
    for (int j = 0; j < NI; j++) {
      int row = m0 + wrow * (BM / 2) + i * 16 + quad * 4;
      int col = n0 + wcol * (BN / 2) + j * 16 + c16 + cofs;
#pragma unroll
      for (int r = 0; r < 4; r++) {
        if constexpr (CF32) ((float*)Cv)[(size_t)(row + r) * LDC + col] = acc[i][j][r];
        else ((unsigned short*)Cv)[(size_t)(row + r) * LDC + col] = f2bf(acc[i][j][r]);
      }
    }
}

// =====================================================================
extern "C" void kernel_launch(void* const* d_in, const int* in_sizes, int n_in,
                              void* d_out, int out_size, void* d_ws, size_t ws_size,
                              hipStream_t stream) {
  const float* x = (const float*)d_in[0];
  const float* Wq = (const float*)d_in[2];
  const float* Wk = (const float*)d_in[3];
  const float* Wv = (const float*)d_in[4];
  const float* Wo = (const float*)d_in[5];
  float* out = (float*)d_out;

  unsigned short* QKV = (unsigned short*)d_ws;                 // [4096][3072] bf16 (24MB)
  unsigned short* Wb = QKV + (size_t)NTOK * 3072;              // 4 x [1024][1024] bf16 (8MB)
  unsigned short* Xb = Wb + (size_t)4 * 1024 * 1024;           // [4096][1024] bf16 (8MB), == AT
  unsigned short* AT = Xb;

  if (ws_size >= (size_t)40 * 1024 * 1024) {
    // convert: 4096 blocks, exactly one vec8 per thread (r16)
    cvt_all<<<dim3(4096), 256, 0, stream>>>(x, Wq, Wk, Wv, Wo, Xb, Wb);
    // fused QKV projection: 256x192, TWO phases via 3-buffer B (r15, best)
    gemm_2ph_w192<<<dim3(256), 512, 0, stream>>>(Xb, Wb, QKV);
    // flash attention v14: single-barrier pipeline, Vt double-buffer
    attn_kernel<<<dim3(NH, 2, 32), 256, 0, stream>>>(QKV, AT);
    // output projection: gemm_lds structure with BK=128 (r14)
    gemm_op_bk128<<<dim3(32, 16), 256, 0, stream>>>(
        AT, Wb + (size_t)3 * 1024 * 1024, out);
  } else {
    unsigned short* QKV2 = (unsigned short*)d_ws;
    unsigned short* AT2 = QKV2 + (size_t)NTOK * 3072;
    gemm_bt<128, 128, 3072, true, false><<<dim3(8, 32, 3), 256, 0, stream>>>(x, Wq, Wk, Wv, QKV2);
    attn_kernel<<<dim3(NH, 2, 32), 256, 0, stream>>>(QKV2, AT2);
    gemm_bt<64, 64, 1024, false, true><<<dim3(16, 64, 1), 256, 0, stream>>>(AT2, Wo, Wo, Wo, out);
  }
}